// Round 12
// baseline (103.604 us; speedup 1.0000x reference)
//
#include <hip/hip_runtime.h>
#include <math.h>

#define HEADS 4
#define HD    64
#define CCH   256
#define NB    4
#define HH    48
#define WW    48
#define NN    (HH*WW)            // 2304
#define EPSBN 1e-5f
#define KSCL  0.18033688f        // 0.125 * log2(e)  (folded into K weights/bias)
#define BCN   (NB*CCH*NN)        // 2,359,296 elements
#define NSP   4                  // kv splits

typedef unsigned short ushort_t;
typedef __attribute__((ext_vector_type(8))) short bfrag;   // 8 bf16 = 4 VGPR
typedef __attribute__((ext_vector_type(4))) float f32x4;   // MFMA C/D

#define MFMA __builtin_amdgcn_mfma_f32_16x16x32_bf16

static __device__ __forceinline__ ushort_t f2bf(float x) {
    unsigned int u = __float_as_uint(x);
    unsigned int r = (u + 0x7fffu + ((u >> 16) & 1u)) >> 16;   // RNE
    return (ushort_t)r;
}
static __device__ __forceinline__ unsigned cvtpk(float lo, float hi) {
    unsigned r;
    asm("v_cvt_pk_bf16_f32 %0, %1, %2" : "=v"(r) : "v"(lo), "v"(hi));
    return r;
}
static __device__ __forceinline__ float bflo(unsigned u) { return __uint_as_float(u << 16); }
static __device__ __forceinline__ float bfhi(unsigned u) { return __uint_as_float(u & 0xffff0000u); }

static __device__ __forceinline__ void gload16(const void* g, void* l) {
    __builtin_amdgcn_global_load_lds(
        (const __attribute__((address_space(1))) void*)g,
        (__attribute__((address_space(3))) void*)l, 16, 0, 0);
}

// ---------------------------------------------------------------------------
// prep (merged): blocks < 3456: fp32 [b][c][n] -> bf16 [b][n][c] for q,k,v.
// blocks >= 3456: fold BN into weights -> bf16 W'[4][256][256], bias'[4][256];
// pe weights tap-major bf16; kmax2 zero-init.
// ---------------------------------------------------------------------------
struct PrepWP {
    const float* W[4];
    const float* G[4]; const float* Bb[4]; const float* Mm[4]; const float* Vv[4];
    const float* pew; const float* peg; const float* peb; const float* pem; const float* pev;
    ushort_t* W4; float* bias4; ushort_t* pw2; float* pbias; float* kmax2;
    const float* q; const float* k; const float* v; ushort_t* Xt;
};
__global__ __launch_bounds__(256)
void prep_kernel(PrepWP P)
{
    const int blk = blockIdx.x, tid = threadIdx.x;
    if (blk < 3456) {            // transpose path
        const int t  = blk / 1152;
        const int r  = blk % 1152;
        const int b  = r / 288;
        const int r2 = r % 288;
        const int n0 = (r2 >> 3) * 64;
        const int cb = (r2 & 7) * 32;
        const float* X = (t == 0) ? P.q : (t == 1) ? P.k : P.v;
        ushort_t* O = P.Xt + (size_t)t * BCN;
        const int lane = tid & 63;
        const int c0   = cb + (tid >> 6) * 8;
        const float* src = X + ((size_t)(b * CCH + c0) * NN + n0 + lane);
        float vv[8];
#pragma unroll
        for (int j = 0; j < 8; ++j) vv[j] = src[(size_t)j * NN];
        uint4 u;
        u.x = cvtpk(vv[0], vv[1]); u.y = cvtpk(vv[2], vv[3]);
        u.z = cvtpk(vv[4], vv[5]); u.w = cvtpk(vv[6], vv[7]);
        *(uint4*)&O[((size_t)b * NN + n0 + lane) * CCH + c0] = u;
        return;
    }
    const int wb = blk - 3456;
    if (wb == 128) {
        int c = tid;
        float s = P.peg[c] * rsqrtf(P.pev[c] + EPSBN);
        for (int tap = 0; tap < 9; ++tap)
            P.pw2[tap * CCH + c] = f2bf(P.pew[c * 9 + tap] * s);
        P.pbias[c] = P.peb[c] - P.pem[c] * s;
        if (tid < 16) P.kmax2[tid] = 0.f;
        return;
    }
    int g  = wb * 256 + tid;
    int cv = g >> 13;
    int o  = (g >> 5) & 255;
    int c8 = g & 31;
    float s  = P.G[cv][o] * rsqrtf(P.Vv[cv][o] + EPSBN);
    float s2 = (cv == 1) ? s * KSCL : s;
    const float* w = P.W[cv] + (size_t)o * CCH + c8 * 8;
    uint4 u;
    u.x = cvtpk(w[0]*s2, w[1]*s2); u.y = cvtpk(w[2]*s2, w[3]*s2);
    u.z = cvtpk(w[4]*s2, w[5]*s2); u.w = cvtpk(w[6]*s2, w[7]*s2);
    *(uint4*)&P.W4[((size_t)cv * CCH + o) * CCH + c8 * 8] = u;
    if (c8 == 0) {
        float bb = (P.Bb[cv][o] - P.Mm[cv][o] * s);
        P.bias4[cv * CCH + o] = (cv == 1) ? bb * KSCL : bb;
    }
}

// ---------------------------------------------------------------------------
// bf16 MFMA 1x1-conv GEMM, 64x64 tile, full K=256 staged once.
// PROJ==0: z = which*4+b, which 0(q),1(k) -> bf16 [b][h][n][d]; 2(v) -> bf16 [b][c][n]
//          which==1 additionally accumulates per-head max row-norm^2 (atomicMax).
// PROJ==1: which=3, fp32 [b][c][n] -> d_out
// ---------------------------------------------------------------------------
template<int PROJ>
__global__ __launch_bounds__(256)
void conv_gemm(const ushort_t* __restrict__ T, const ushort_t* __restrict__ W4,
               const float* __restrict__ bias4,
               ushort_t* __restrict__ qnd, ushort_t* __restrict__ knd,
               ushort_t* __restrict__ vcn, float* __restrict__ outf,
               float* __restrict__ kmax2)
{
    __shared__ ushort_t Ts[64][264];
    __shared__ ushort_t Ws[64][264];
    const int nt = blockIdx.x, ot = blockIdx.y, z = blockIdx.z;
    const int which = PROJ ? 3 : (z >> 2);
    const int b = z & 3;
    const int tid = threadIdx.x;
    const int n0 = nt * 64, o0 = ot * 64;
    const ushort_t* Tsrc = T + (PROJ ? (size_t)0 : (size_t)which * BCN) + ((size_t)b * NN + n0) * CCH;
    const ushort_t* Wsrc = W4 + (size_t)which * CCH * CCH + (size_t)o0 * CCH;
    const float*    bias = bias4 + which * CCH;
#pragma unroll
    for (int i = 0; i < 8; ++i) {
        int idx = tid + i * 256;
        int r = idx >> 5, c16 = idx & 31;
        *(uint4*)&Ts[r][c16 * 8] = *(const uint4*)&Tsrc[(size_t)r * CCH + c16 * 8];
        *(uint4*)&Ws[r][c16 * 8] = *(const uint4*)&Wsrc[(size_t)r * CCH + c16 * 8];
    }
    __syncthreads();
    const int wv = tid >> 6, lane = tid & 63, lr = lane & 15, lg = lane >> 4;
    const int qn = (wv >> 1) * 32, qo = (wv & 1) * 32;
    f32x4 acc[2][2];
#pragma unroll
    for (int i = 0; i < 2; ++i)
#pragma unroll
        for (int j = 0; j < 2; ++j) acc[i][j] = (f32x4){0.f, 0.f, 0.f, 0.f};

    if (!PROJ && (z >> 2) < 2) {
#pragma unroll
        for (int k8 = 0; k8 < 8; ++k8) {
            const int kc = k8 * 32 + lg * 8;
            bfrag ta0 = *(const bfrag*)&Ts[qn + lr][kc];
            bfrag ta1 = *(const bfrag*)&Ts[qn + 16 + lr][kc];
            bfrag wa0 = *(const bfrag*)&Ws[qo + lr][kc];
            bfrag wa1 = *(const bfrag*)&Ws[qo + 16 + lr][kc];
            acc[0][0] = MFMA(ta0, wa0, acc[0][0], 0, 0, 0);
            acc[0][1] = MFMA(ta0, wa1, acc[0][1], 0, 0, 0);
            acc[1][0] = MFMA(ta1, wa0, acc[1][0], 0, 0, 0);
            acc[1][1] = MFMA(ta1, wa1, acc[1][1], 0, 0, 0);
        }
    } else {
#pragma unroll
        for (int k8 = 0; k8 < 8; ++k8) {
            const int kc = k8 * 32 + lg * 8;
            bfrag ta0 = *(const bfrag*)&Ts[qn + lr][kc];
            bfrag ta1 = *(const bfrag*)&Ts[qn + 16 + lr][kc];
            bfrag wa0 = *(const bfrag*)&Ws[qo + lr][kc];
            bfrag wa1 = *(const bfrag*)&Ws[qo + 16 + lr][kc];
            acc[0][0] = MFMA(wa0, ta0, acc[0][0], 0, 0, 0);
            acc[0][1] = MFMA(wa0, ta1, acc[0][1], 0, 0, 0);
            acc[1][0] = MFMA(wa1, ta0, acc[1][0], 0, 0, 0);
            acc[1][1] = MFMA(wa1, ta1, acc[1][1], 0, 0, 0);
        }
    }

    __syncthreads();   // Ts/Ws dead; overlay epilogue staging
    if (!PROJ && which < 2) {
        ushort_t (*Ot)[72] = (ushort_t(*)[72])Ts;
        float bv[2] = { bias[o0 + qo + lr], bias[o0 + qo + 16 + lr] };
#pragma unroll
        for (int i = 0; i < 2; ++i)
#pragma unroll
            for (int j = 0; j < 2; ++j)
#pragma unroll
                for (int r = 0; r < 4; ++r)
                    Ot[qn + i * 16 + lg * 4 + r][qo + j * 16 + lr] = f2bf(acc[i][j][r] + bv[j]);
        __syncthreads();
        ushort_t* out = (which == 0) ? qnd : knd;
        for (int idx = tid; idx < 512; idx += 256) {
            int r = idx >> 3, sg = idx & 7;
            *(uint4*)&out[(((size_t)b * HEADS + ot) * NN + n0 + r) * HD + sg * 8] =
                *(const uint4*)&Ot[r][sg * 8];
        }
        if (which == 1 && tid < 64) {   // per-head max row-norm^2 of K'
            float s = 0.f;
#pragma unroll
            for (int j = 0; j < 8; ++j) {
                uint4 u = *(const uint4*)&Ot[tid][j * 8];
                s += bflo(u.x)*bflo(u.x) + bfhi(u.x)*bfhi(u.x);
                s += bflo(u.y)*bflo(u.y) + bfhi(u.y)*bfhi(u.y);
                s += bflo(u.z)*bflo(u.z) + bfhi(u.z)*bfhi(u.z);
                s += bflo(u.w)*bflo(u.w) + bfhi(u.w)*bfhi(u.w);
            }
            atomicMax((unsigned*)&kmax2[b * HEADS + ot], __float_as_uint(s));
        }
    } else if (!PROJ) {
        ushort_t (*Ot)[72] = (ushort_t(*)[72])Ts;
#pragma unroll
        for (int i = 0; i < 2; ++i)
#pragma unroll
            for (int r = 0; r < 4; ++r) {
                float bv = bias[o0 + qo + i * 16 + lg * 4 + r];
#pragma unroll
                for (int j = 0; j < 2; ++j)
                    Ot[qo + i * 16 + lg * 4 + r][qn + j * 16 + lr] = f2bf(acc[i][j][r] + bv);
            }
        __syncthreads();
        for (int idx = tid; idx < 512; idx += 256) {
            int r = idx >> 3, sg = idx & 7;
            *(uint4*)&vcn[((size_t)b * CCH + o0 + r) * NN + n0 + sg * 8] =
                *(const uint4*)&Ot[r][sg * 8];
        }
    } else {
        float (*Of)[68] = (float(*)[68])Ts;
#pragma unroll
        for (int i = 0; i < 2; ++i)
#pragma unroll
            for (int r = 0; r < 4; ++r) {
                float bv = bias[o0 + qo + i * 16 + lg * 4 + r];
#pragma unroll
                for (int j = 0; j < 2; ++j)
                    Of[qo + i * 16 + lg * 4 + r][qn + j * 16 + lr] = acc[i][j][r] + bv;
            }
        __syncthreads();
        for (int idx = tid; idx < 1024; idx += 256) {
            int r = idx >> 4, c4 = idx & 15;
            *(float4*)&outf[((size_t)b * CCH + o0 + r) * NN + n0 + c4 * 4] =
                *(const float4*)&Of[r][c4 * 4];
        }
    }
}

// ---------------------------------------------------------------------------
// MFMA flash attention: 4 waves x 64 q = 256 q/block, Bc=64, kv-split x4.
// K/V LDS reads amortized over 64 q per wave (the per-CU LDS pipe is the
// bottleneck; traffic scales with waves-per-unit-work). Per-qc P sub-regions
// (2KB each) -> immediate writes, low VGPR. Counted-vmcnt 2-barrier pipeline.
// Norm-bound fixed softmax max in MFMA C-init; l via ones-row MFMA.
// ---------------------------------------------------------------------------
__global__ __launch_bounds__(256, 2)
void attn_kernel(const ushort_t* __restrict__ Qnd,   // bf16 [b][h][n][d]
                 const ushort_t* __restrict__ Knd,   // bf16 [b][h][n][d] *KSCL
                 const ushort_t* __restrict__ Vcn,   // bf16 [b][c][n]
                 const float* __restrict__ kmax2,    // [16] max row-norm^2
                 ushort_t* __restrict__ Op,          // bf16 [4][b][n][c]
                 float* __restrict__ Larr)           // fp32 [4][16][NN]
{
    __shared__ __align__(16) char smem[65536];
    // K2 @0: [2][8192]sw ; V2 @16384: [2][8192]sw ; P @32768: [4 wv][4 qc][2048]

    const int tid = threadIdx.x;
    const int lin0 = blockIdx.x + 9 * blockIdx.y + 144 * blockIdx.z;
    const int w    = (lin0 & 7) * 72 + (lin0 >> 3);   // XCD-chunked remap (576=8*72)
    const int qt = w % 9;
    const int bh = (w / 9) & 15;
    const int sp = w / 144;
    const int b = bh >> 2, h = bh & 3;
    const int lane = tid & 63, wv = tid >> 6;
    const int lr = lane & 15, lg = lane >> 4;
    const int lrow = lane >> 3, lslot = (lane & 7) ^ lrow;
    const int n0 = qt * 256;
    const size_t ndb = (size_t)(b * HEADS + h) * NN * HD;
    const size_t cnb = ((size_t)b * CCH + h * HD) * NN;

    // staging pointers (pre-swizzled global source, linear LDS dest)
    const char* kgp = (const char*)(Knd + ndb) + (size_t)(sp * 576 + wv * 16 + lrow) * 128 + lslot * 16;
    const char* vgp = (const char*)(Vcn + cnb + sp * 576) + (size_t)(wv * 16 + lrow) * (NN * 2) + lslot * 16;
    char* kls = smem + wv * 2048;
    char* vls = smem + 16384 + wv * 2048;

#define STAGE(buf, t) do { \
    const char* kp_ = kgp + (size_t)(t) * 8192; \
    const char* vp_ = vgp + (size_t)(t) * 128; \
    char* kd_ = kls + (buf) * 8192; \
    char* vd_ = vls + (buf) * 8192; \
    gload16(kp_,              kd_); \
    gload16(kp_ + 1024,       kd_ + 1024); \
    gload16(vp_,              vd_); \
    gload16(vp_ + 8 * (NN*2), vd_ + 1024); \
} while (0)

    // Q fragments: 64 q rows per wave (4 x 16)
    bfrag qb[4][2];
    {
        const ushort_t* qbase = Qnd + ndb + (size_t)(n0 + wv * 64 + lr) * HD;
#pragma unroll
        for (int qc = 0; qc < 4; ++qc) {
            qb[qc][0] = *(const bfrag*)&qbase[(size_t)qc * 16 * HD + lg * 8];
            qb[qc][1] = *(const bfrag*)&qbase[(size_t)qc * 16 * HD + 32 + lg * 8];
        }
    }
    // fixed softmax bound m0 = |q| * max|k'| + margin
    float m0[4];
    {
        const float kmx = sqrtf(kmax2[bh]);
#pragma unroll
        for (int qc = 0; qc < 4; ++qc) {
            const unsigned* u0 = (const unsigned*)&qb[qc][0];
            const unsigned* u1 = (const unsigned*)&qb[qc][1];
            float s = 0.f;
#pragma unroll
            for (int j = 0; j < 4; ++j) {
                float a0 = bflo(u0[j]), a1 = bfhi(u0[j]);
                float b0 = bflo(u1[j]), b1 = bfhi(u1[j]);
                s += a0*a0 + a1*a1 + b0*b0 + b1*b1;
            }
            s += __shfl_xor(s, 16);
            s += __shfl_xor(s, 32);
            m0[qc] = sqrtf(s) * kmx + 0.5f;
        }
    }
    // ones A-fragment (row 0 = 1.0, rows 1..15 = 0) for l accumulation
    bfrag ones_f;
    {
        short ov = (lr == 0) ? (short)0x3F80 : (short)0;
#pragma unroll
        for (int j = 0; j < 8; ++j) ones_f[j] = ov;
    }

    f32x4 o[4][4], o4[4];
#pragma unroll
    for (int qc = 0; qc < 4; ++qc) {
        o4[qc] = (f32x4){0.f, 0.f, 0.f, 0.f};
#pragma unroll
        for (int db = 0; db < 4; ++db) o[qc][db] = (f32x4){0.f, 0.f, 0.f, 0.f};
    }

    const int sw0 = (lg ^ (lr & 7)) << 4;
    const int sw1 = ((4 + lg) ^ (lr & 7)) << 4;
    char* Pw = smem + 32768 + wv * 8192;   // wave's P: 4 qc x 2KB sub-regions

    STAGE(0, 0);    // tile-0 loads in flight

    for (int t = 0; t < 9; ++t) {
        const int cur = t & 1;
        if (t < 8) {
            STAGE(cur ^ 1, t + 1);                            // prefetch t+1
            asm volatile("s_waitcnt vmcnt(4)" ::: "memory");  // t done, t+1 flying
        } else {
            asm volatile("s_waitcnt vmcnt(0)" ::: "memory");
        }
        __builtin_amdgcn_s_barrier();    // all waves' tile-t data staged
        const char* Kb = smem + cur * 8192;
        const char* Vb = smem + 16384 + cur * 8192;

        // QK: S^T[64 kk][64 q], C-init = -m0; exp+pack+P-write fused per (kb,qc)
        __builtin_amdgcn_s_setprio(1);
#pragma unroll
        for (int kb = 0; kb < 4; ++kb) {
            const char* krow = Kb + (kb * 16 + lr) * 128;
            bfrag ka0 = *(const bfrag*)(krow + sw0);
            bfrag ka1 = *(const bfrag*)(krow + sw1);
            const int slot = (2 * kb + (lg >> 1)) ^ (lr & 7);
#pragma unroll
            for (int qc = 0; qc < 4; ++qc) {
                f32x4 z = (f32x4){-m0[qc], -m0[qc], -m0[qc], -m0[qc]};
                z = MFMA(ka0, qb[qc][0], z, 0, 0, 0);
                z = MFMA(ka1, qb[qc][1], z, 0, 0, 0);
                uint2 u;
                u.x = cvtpk(exp2f(z[0]), exp2f(z[1]));
                u.y = cvtpk(exp2f(z[2]), exp2f(z[3]));
                *(uint2*)(Pw + qc * 2048 + lr * 128 + slot * 16 + (lg & 1) * 8) = u;
            }
        }
        __builtin_amdgcn_s_setprio(0);

        // read back P fragments (per-wave private; compiler inserts lgkm waits)
        bfrag pb[4][2];
#pragma unroll
        for (int qc = 0; qc < 4; ++qc) {
            const char* prow = Pw + qc * 2048 + lr * 128;
            pb[qc][0] = *(const bfrag*)(prow + sw0);
            pb[qc][1] = *(const bfrag*)(prow + sw1);
        }

        // PV: O^T[d][q] += V^T * P^T ; l via ones row
        __builtin_amdgcn_s_setprio(1);
#pragma unroll
        for (int db = 0; db < 4; ++db) {
            const char* vrow = Vb + (db * 16 + lr) * 128;
            bfrag va0 = *(const bfrag*)(vrow + sw0);
            bfrag va1 = *(const bfrag*)(vrow + sw1);
#pragma unroll
            for (int qc = 0; qc < 4; ++qc) {
                o[qc][db] = MFMA(va0, pb[qc][0], o[qc][db], 0, 0, 0);
                o[qc][db] = MFMA(va1, pb[qc][1], o[qc][db], 0, 0, 0);
            }
        }
#pragma unroll
        for (int qc = 0; qc < 4; ++qc) {
            o4[qc] = MFMA(ones_f, pb[qc][0], o4[qc], 0, 0, 0);
            o4[qc] = MFMA(ones_f, pb[qc][1], o4[qc], 0, 0, 0);
        }
        __builtin_amdgcn_s_setprio(0);

        __builtin_amdgcn_s_barrier();    // all waves done reading buf[cur]
    }
#undef STAGE

    // epilogue: pack O' bf16, transpose via LDS, coalesced uint4 stores
    if (lg == 0) {
#pragma unroll
        for (int qc = 0; qc < 4; ++qc)
            Larr[(size_t)(sp * 16 + bh) * NN + n0 + wv * 64 + qc * 16 + lr] = o4[qc][0];
    }
    unsigned (*Osb)[36] = (unsigned(*)[36])smem;   // [256][36] u32 = 36864B
#pragma unroll
    for (int qc = 0; qc < 4; ++qc) {
        int row = wv * 64 + qc * 16 + lr;
#pragma unroll
        for (int db = 0; db < 4; ++db) {
            Osb[row][db * 8 + lg * 2 + 0] = cvtpk(o[qc][db][0], o[qc][db][1]);
            Osb[row][db * 8 + lg * 2 + 1] = cvtpk(o[qc][db][2], o[qc][db][3]);
        }
    }
    __syncthreads();
    ushort_t* opb = Op + (size_t)sp * BCN + ((size_t)b * NN + n0) * CCH + h * HD;
    for (int idx = tid; idx < 2048; idx += 256) {
        int n = idx >> 3, s4 = idx & 7;
        *(uint4*)&opb[(size_t)n * CCH + s4 * 8] = *(const uint4*)&Osb[n][s4 * 4];
    }
}

// ---------------------------------------------------------------------------
// fuse: sum kv-splits (bf16 O', shared m0) + depthwise 3x3 BN -> bf16 [b][n][c]
// ---------------------------------------------------------------------------
__global__ __launch_bounds__(256)
void fuse_kernel(const ushort_t* __restrict__ Op, const float* __restrict__ Larr,
                 const ushort_t* __restrict__ Qnd,
                 const ushort_t* __restrict__ pw2, const float* __restrict__ pbias,
                 ushort_t* __restrict__ yt)
{
    const int tid = threadIdx.x;
    const int b  = blockIdx.x / 288;
    const int n0 = (blockIdx.x % 288) * 8;
    const int c8 = tid & 31, ns = tid >> 5;
    const int n  = n0 + ns;
    const int h  = c8 >> 3, c0 = c8 * 8;

    const ushort_t* o0p = Op + ((size_t)b * NN + n) * CCH + c0;
    float acc[8] = {0.f, 0.f, 0.f, 0.f, 0.f, 0.f, 0.f, 0.f};
#pragma unroll
    for (int s = 0; s < NSP; ++s) {
        uint4 u = *(const uint4*)&o0p[(size_t)s * BCN];
        acc[0] += bflo(u.x); acc[1] += bfhi(u.x);
        acc[2] += bflo(u.y); acc[3] += bfhi(u.y);
        acc[4] += bflo(u.z); acc[5] += bfhi(u.z);
        acc[6] += bflo(u.w); acc[7] += bfhi(u.w);
    }
    int mi = (b * HEADS + h) * NN + n;
    float ls = 0.f;
#pragma unroll
    for (int s = 0; s < NSP; ++s) ls += Larr[(size_t)s * 16 * NN + mi];
    float rinv = 1.0f / ls;
#pragma unroll
    for (int j = 0; j < 8; ++j) acc[j] *= rinv;

    const int x = n % WW, y = n / WW;
    const ushort_t* qb = Qnd + (size_t)(b * HEADS + h) * NN * HD + (c8 & 7) * 8;
#pragma unroll
    for (int ky = 0; ky < 3; ++ky) {
        int yy = y + ky - 1;
        if (yy < 0 || yy >= HH) continue;
#pragma unroll
        for (int kx = 0; kx < 3; ++kx) {
            int xx = x + kx - 1;
            if (xx < 0 || xx >= WW) continue;
            int np = yy * WW + xx;
            uint4 qv = *(const uint4*)&qb[(size_t)np * HD];
            uint4 w4 = *(const uint4*)&pw2[(ky * 3 + kx) * CCH + c0];
            acc[0] += bflo(qv.x) * bflo(w4.x); acc[1] += bfhi(qv.x) * bfhi(w4.x);
            acc[2] += bflo(qv.y) * bflo(w4.y); acc[3] += bfhi(qv.y) * bfhi(w4.y);
            acc[4] += bflo(qv.z) * bflo(w4.z); acc[5] += bfhi(qv.z) * bfhi(w4.z);
            acc[6] += bflo(qv.w) * bflo(w4.w); acc[7] += bfhi(qv.w) * bfhi(w4.w);
        }
    }
    float4 p0 = *(const float4*)&pbias[c0];
    float4 p1 = *(const float4*)&pbias[c0 + 4];
    acc[0] += p0.x; acc[1] += p0.y; acc[2] += p0.z; acc[3] += p0.w;
    acc[4] += p1.x; acc[5] += p1.y; acc[6] += p1.z; acc[7] += p1.w;
    uint4 u;
    u.x = cvtpk(acc[0], acc[1]); u.y = cvtpk(acc[2], acc[3]);
    u.z = cvtpk(acc[4], acc[5]); u.w = cvtpk(acc[6], acc[7]);
    *(uint4*)&yt[((size_t)b * NN + n) * CCH + c0] = u;
}

// ---------------------------------------------------------------------------
extern "C" void kernel_launch(void* const* d_in, const int* in_sizes, int n_in,
                              void* d_out, int out_size, void* d_ws, size_t ws_size,
                              hipStream_t stream) {
    char* ws = (char*)d_ws;
    ushort_t* qnd  = (ushort_t*)(ws + 0);
    ushort_t* knd  = (ushort_t*)(ws + 4718592);
    ushort_t* vcn  = (ushort_t*)(ws + 9437184);
    ushort_t* Xt   = (ushort_t*)(ws + 14155776);
    ushort_t* Op   = (ushort_t*)(ws + 14155776);   // bf16 [4][BCN], overlays Xt
    ushort_t* yt   = (ushort_t*)(ws + 4718592);    // overlays knd after attn
    float*    Larr = (float*)   (ws + 33030144);   // [4][16][NN] fp32
    ushort_t* W4   = (ushort_t*)(ws + 33619968);
    float*    bias4= (float*)   (ws + 34144256);
    ushort_t* pw2  = (ushort_t*)(ws + 34148352);
    float*    pbias= (float*)   (ws + 34152960);
    float*    kmax2= (float*)   (ws + 34156032);

    PrepWP P;
    P.W[0] = (const float*)d_in[3]; P.W[1] = (const float*)d_in[4];
    P.W[2] = (const float*)d_in[5]; P.W[3] = (const float*)d_in[6];
    P.G[0]  = (const float*)d_in[8];  P.Bb[0] = (const float*)d_in[9];
    P.Mm[0] = (const float*)d_in[10]; P.Vv[0] = (const float*)d_in[11];
    P.G[1]  = (const float*)d_in[12]; P.Bb[1] = (const float*)d_in[13];
    P.Mm[1] = (const float*)d_in[14]; P.Vv[1] = (const float*)d_in[15];
    P.G[2]  = (const float*)d_in[16]; P.Bb[2] = (const float*)d_in[17];
    P.Mm[2] = (const float*)d_in[18]; P.Vv[2] = (const float*)d_in[19];
    P.G[3]  = (const float*)d_in[24]; P.Bb[3] = (const float*)d_in[25];
    P.Mm[3] = (const float*)d_in[26]; P.Vv[3] = (const float*)d_in[27];
    P.pew = (const float*)d_in[7];
    P.peg = (const float*)d_in[20]; P.peb = (const float*)d_in[21];
    P.pem = (const float*)d_in[22]; P.pev = (const float*)d_in[23];
    P.W4 = W4; P.bias4 = bias4; P.pw2 = pw2; P.pbias = pbias; P.kmax2 = kmax2;
    P.q = (const float*)d_in[0]; P.k = (const float*)d_in[1];
    P.v = (const float*)d_in[2]; P.Xt = Xt;

    prep_kernel<<<3585, 256, 0, stream>>>(P);

    conv_gemm<0><<<dim3(36, 4, 12), 256, 0, stream>>>(Xt, W4, bias4, qnd, knd, vcn, nullptr, kmax2);

    attn_kernel<<<dim3(9, 16, NSP), 256, 0, stream>>>(qnd, knd, vcn, kmax2, Op, Larr);

    fuse_kernel<<<1152, 256, 0, stream>>>(Op, Larr, qnd, pw2, pbias, yt);

    conv_gemm<1><<<dim3(36, 4, 4), 256, 0, stream>>>(yt, W4, bias4, nullptr, nullptr, nullptr,
                                                     (float*)d_out, nullptr);
}

// Round 13
// 91.661 us; speedup vs baseline: 1.1303x; 1.1303x over previous
//
#include <hip/hip_runtime.h>
#include <math.h>

#define HEADS 4
#define HD    64
#define CCH   256
#define NB    4
#define HH    48
#define WW    48
#define NN    (HH*WW)            // 2304
#define EPSBN 1e-5f
#define KSCL  0.18033688f        // 0.125 * log2(e)  (folded into K weights/bias)
#define BCN   (NB*CCH*NN)        // 2,359,296 elements
#define NSP   4                  // kv splits

typedef unsigned short ushort_t;
typedef __attribute__((ext_vector_type(8))) short bfrag;    // 8 bf16 = 4 VGPR
typedef __attribute__((ext_vector_type(4))) float f32x4;    // 16x16 C/D
typedef __attribute__((ext_vector_type(16))) float f32x16;  // 32x32 C/D

#define MFMA   __builtin_amdgcn_mfma_f32_16x16x32_bf16
#define MFMA32 __builtin_amdgcn_mfma_f32_32x32x16_bf16

static __device__ __forceinline__ ushort_t f2bf(float x) {
    unsigned int u = __float_as_uint(x);
    unsigned int r = (u + 0x7fffu + ((u >> 16) & 1u)) >> 16;   // RNE
    return (ushort_t)r;
}
static __device__ __forceinline__ unsigned cvtpk(float lo, float hi) {
    unsigned r;
    asm("v_cvt_pk_bf16_f32 %0, %1, %2" : "=v"(r) : "v"(lo), "v"(hi));
    return r;
}
static __device__ __forceinline__ float bflo(unsigned u) { return __uint_as_float(u << 16); }
static __device__ __forceinline__ float bfhi(unsigned u) { return __uint_as_float(u & 0xffff0000u); }

static __device__ __forceinline__ void gload16(const void* g, void* l) {
    __builtin_amdgcn_global_load_lds(
        (const __attribute__((address_space(1))) void*)g,
        (__attribute__((address_space(3))) void*)l, 16, 0, 0);
}

// ---------------------------------------------------------------------------
// prep (merged): blocks < 3456: fp32 [b][c][n] -> bf16 [b][n][c] for q,k,v.
// blocks >= 3456: fold BN into weights; pe weights tap-major; kmax2 init.
// ---------------------------------------------------------------------------
struct PrepWP {
    const float* W[4];
    const float* G[4]; const float* Bb[4]; const float* Mm[4]; const float* Vv[4];
    const float* pew; const float* peg; const float* peb; const float* pem; const float* pev;
    ushort_t* W4; float* bias4; ushort_t* pw2; float* pbias; float* kmax2;
    const float* q; const float* k; const float* v; ushort_t* Xt;
};
__global__ __launch_bounds__(256)
void prep_kernel(PrepWP P)
{
    const int blk = blockIdx.x, tid = threadIdx.x;
    if (blk < 3456) {            // transpose path
        const int t  = blk / 1152;
        const int r  = blk % 1152;
        const int b  = r / 288;
        const int r2 = r % 288;
        const int n0 = (r2 >> 3) * 64;
        const int cb = (r2 & 7) * 32;
        const float* X = (t == 0) ? P.q : (t == 1) ? P.k : P.v;
        ushort_t* O = P.Xt + (size_t)t * BCN;
        const int lane = tid & 63;
        const int c0   = cb + (tid >> 6) * 8;
        const float* src = X + ((size_t)(b * CCH + c0) * NN + n0 + lane);
        float vv[8];
#pragma unroll
        for (int j = 0; j < 8; ++j) vv[j] = src[(size_t)j * NN];
        uint4 u;
        u.x = cvtpk(vv[0], vv[1]); u.y = cvtpk(vv[2], vv[3]);
        u.z = cvtpk(vv[4], vv[5]); u.w = cvtpk(vv[6], vv[7]);
        *(uint4*)&O[((size_t)b * NN + n0 + lane) * CCH + c0] = u;
        return;
    }
    const int wb = blk - 3456;
    if (wb == 128) {
        int c = tid;
        float s = P.peg[c] * rsqrtf(P.pev[c] + EPSBN);
        for (int tap = 0; tap < 9; ++tap)
            P.pw2[tap * CCH + c] = f2bf(P.pew[c * 9 + tap] * s);
        P.pbias[c] = P.peb[c] - P.pem[c] * s;
        if (tid < 16) P.kmax2[tid] = 0.f;
        return;
    }
    int g  = wb * 256 + tid;
    int cv = g >> 13;
    int o  = (g >> 5) & 255;
    int c8 = g & 31;
    float s  = P.G[cv][o] * rsqrtf(P.Vv[cv][o] + EPSBN);
    float s2 = (cv == 1) ? s * KSCL : s;
    const float* w = P.W[cv] + (size_t)o * CCH + c8 * 8;
    uint4 u;
    u.x = cvtpk(w[0]*s2, w[1]*s2); u.y = cvtpk(w[2]*s2, w[3]*s2);
    u.z = cvtpk(w[4]*s2, w[5]*s2); u.w = cvtpk(w[6]*s2, w[7]*s2);
    *(uint4*)&P.W4[((size_t)cv * CCH + o) * CCH + c8 * 8] = u;
    if (c8 == 0) {
        float bb = (P.Bb[cv][o] - P.Mm[cv][o] * s);
        P.bias4[cv * CCH + o] = (cv == 1) ? bb * KSCL : bb;
    }
}

// ---------------------------------------------------------------------------
// bf16 MFMA 1x1-conv GEMM, 64x64 tile, full K=256 staged once.
// ---------------------------------------------------------------------------
template<int PROJ>
__global__ __launch_bounds__(256)
void conv_gemm(const ushort_t* __restrict__ T, const ushort_t* __restrict__ W4,
               const float* __restrict__ bias4,
               ushort_t* __restrict__ qnd, ushort_t* __restrict__ knd,
               ushort_t* __restrict__ vcn, float* __restrict__ outf,
               float* __restrict__ kmax2)
{
    __shared__ ushort_t Ts[64][264];
    __shared__ ushort_t Ws[64][264];
    const int nt = blockIdx.x, ot = blockIdx.y, z = blockIdx.z;
    const int which = PROJ ? 3 : (z >> 2);
    const int b = z & 3;
    const int tid = threadIdx.x;
    const int n0 = nt * 64, o0 = ot * 64;
    const ushort_t* Tsrc = T + (PROJ ? (size_t)0 : (size_t)which * BCN) + ((size_t)b * NN + n0) * CCH;
    const ushort_t* Wsrc = W4 + (size_t)which * CCH * CCH + (size_t)o0 * CCH;
    const float*    bias = bias4 + which * CCH;
#pragma unroll
    for (int i = 0; i < 8; ++i) {
        int idx = tid + i * 256;
        int r = idx >> 5, c16 = idx & 31;
        *(uint4*)&Ts[r][c16 * 8] = *(const uint4*)&Tsrc[(size_t)r * CCH + c16 * 8];
        *(uint4*)&Ws[r][c16 * 8] = *(const uint4*)&Wsrc[(size_t)r * CCH + c16 * 8];
    }
    __syncthreads();
    const int wv = tid >> 6, lane = tid & 63, lr = lane & 15, lg = lane >> 4;
    const int qn = (wv >> 1) * 32, qo = (wv & 1) * 32;
    f32x4 acc[2][2];
#pragma unroll
    for (int i = 0; i < 2; ++i)
#pragma unroll
        for (int j = 0; j < 2; ++j) acc[i][j] = (f32x4){0.f, 0.f, 0.f, 0.f};

    if (!PROJ && (z >> 2) < 2) {
#pragma unroll
        for (int k8 = 0; k8 < 8; ++k8) {
            const int kc = k8 * 32 + lg * 8;
            bfrag ta0 = *(const bfrag*)&Ts[qn + lr][kc];
            bfrag ta1 = *(const bfrag*)&Ts[qn + 16 + lr][kc];
            bfrag wa0 = *(const bfrag*)&Ws[qo + lr][kc];
            bfrag wa1 = *(const bfrag*)&Ws[qo + 16 + lr][kc];
            acc[0][0] = MFMA(ta0, wa0, acc[0][0], 0, 0, 0);
            acc[0][1] = MFMA(ta0, wa1, acc[0][1], 0, 0, 0);
            acc[1][0] = MFMA(ta1, wa0, acc[1][0], 0, 0, 0);
            acc[1][1] = MFMA(ta1, wa1, acc[1][1], 0, 0, 0);
        }
    } else {
#pragma unroll
        for (int k8 = 0; k8 < 8; ++k8) {
            const int kc = k8 * 32 + lg * 8;
            bfrag ta0 = *(const bfrag*)&Ts[qn + lr][kc];
            bfrag ta1 = *(const bfrag*)&Ts[qn + 16 + lr][kc];
            bfrag wa0 = *(const bfrag*)&Ws[qo + lr][kc];
            bfrag wa1 = *(const bfrag*)&Ws[qo + 16 + lr][kc];
            acc[0][0] = MFMA(wa0, ta0, acc[0][0], 0, 0, 0);
            acc[0][1] = MFMA(wa0, ta1, acc[0][1], 0, 0, 0);
            acc[1][0] = MFMA(wa1, ta0, acc[1][0], 0, 0, 0);
            acc[1][1] = MFMA(wa1, ta1, acc[1][1], 0, 0, 0);
        }
    }

    __syncthreads();   // Ts/Ws dead; overlay epilogue staging
    if (!PROJ && which < 2) {
        ushort_t (*Ot)[72] = (ushort_t(*)[72])Ts;
        float bv[2] = { bias[o0 + qo + lr], bias[o0 + qo + 16 + lr] };
#pragma unroll
        for (int i = 0; i < 2; ++i)
#pragma unroll
            for (int j = 0; j < 2; ++j)
#pragma unroll
                for (int r = 0; r < 4; ++r)
                    Ot[qn + i * 16 + lg * 4 + r][qo + j * 16 + lr] = f2bf(acc[i][j][r] + bv[j]);
        __syncthreads();
        ushort_t* out = (which == 0) ? qnd : knd;
        for (int idx = tid; idx < 512; idx += 256) {
            int r = idx >> 3, sg = idx & 7;
            *(uint4*)&out[(((size_t)b * HEADS + ot) * NN + n0 + r) * HD + sg * 8] =
                *(const uint4*)&Ot[r][sg * 8];
        }
        if (which == 1 && tid < 64) {   // per-head max row-norm^2 of K'
            float s = 0.f;
#pragma unroll
            for (int j = 0; j < 8; ++j) {
                uint4 u = *(const uint4*)&Ot[tid][j * 8];
                s += bflo(u.x)*bflo(u.x) + bfhi(u.x)*bfhi(u.x);
                s += bflo(u.y)*bflo(u.y) + bfhi(u.y)*bfhi(u.y);
                s += bflo(u.z)*bflo(u.z) + bfhi(u.z)*bfhi(u.z);
                s += bflo(u.w)*bflo(u.w) + bfhi(u.w)*bfhi(u.w);
            }
            atomicMax((unsigned*)&kmax2[b * HEADS + ot], __float_as_uint(s));
        }
    } else if (!PROJ) {
        ushort_t (*Ot)[72] = (ushort_t(*)[72])Ts;
#pragma unroll
        for (int i = 0; i < 2; ++i)
#pragma unroll
            for (int r = 0; r < 4; ++r) {
                float bv = bias[o0 + qo + i * 16 + lg * 4 + r];
#pragma unroll
                for (int j = 0; j < 2; ++j)
                    Ot[qo + i * 16 + lg * 4 + r][qn + j * 16 + lr] = f2bf(acc[i][j][r] + bv);
            }
        __syncthreads();
        for (int idx = tid; idx < 512; idx += 256) {
            int r = idx >> 3, sg = idx & 7;
            *(uint4*)&vcn[((size_t)b * CCH + o0 + r) * NN + n0 + sg * 8] =
                *(const uint4*)&Ot[r][sg * 8];
        }
    } else {
        float (*Of)[68] = (float(*)[68])Ts;
#pragma unroll
        for (int i = 0; i < 2; ++i)
#pragma unroll
            for (int r = 0; r < 4; ++r) {
                float bv = bias[o0 + qo + i * 16 + lg * 4 + r];
#pragma unroll
                for (int j = 0; j < 2; ++j)
                    Of[qo + i * 16 + lg * 4 + r][qn + j * 16 + lr] = acc[i][j][r] + bv;
            }
        __syncthreads();
        for (int idx = tid; idx < 1024; idx += 256) {
            int r = idx >> 4, c4 = idx & 15;
            *(float4*)&outf[((size_t)b * CCH + o0 + r) * NN + n0 + c4 * 4] =
                *(const float4*)&Of[r][c4 * 4];
        }
    }
}

// ---------------------------------------------------------------------------
// MFMA flash attention, 32x32x16 shape: 4 waves x 32 q, Bc=64, kv-split x4.
// P stays IN REGISTERS: S^T C/D layout + cvt_pk + v_permlane32_swap build the
// PV B-fragments directly (no LDS round-trip, no ones-row MFMA; l = in-lane
// sum + one cross-half shuffle). LDS 32KB = K dbuf 16K + V dbuf 16K.
// Counted-vmcnt 2-barrier pipeline; norm-bound fixed softmax max in C-init.
// ---------------------------------------------------------------------------
__global__ __launch_bounds__(256, 4)
void attn_kernel(const ushort_t* __restrict__ Qnd,   // bf16 [b][h][n][d]
                 const ushort_t* __restrict__ Knd,   // bf16 [b][h][n][d] *KSCL
                 const ushort_t* __restrict__ Vcn,   // bf16 [b][c][n]
                 const float* __restrict__ kmax2,    // [16] max row-norm^2
                 ushort_t* __restrict__ Op,          // bf16 [4][b][n][c]
                 float* __restrict__ Larr)           // fp32 [4][16][NN]
{
    __shared__ __align__(16) char smem[32768];
    // K2 @0: [2][8192]sw ; V2 @16384: [2][8192]sw. Epilogue: Osb overlay.

    const int tid = threadIdx.x;
    const int lin0 = blockIdx.x + 18 * blockIdx.y + 288 * blockIdx.z;
    const int w    = (lin0 & 7) * 144 + (lin0 >> 3);   // XCD-chunked remap (1152=8*144)
    const int qt = w % 18;
    const int bh = (w / 18) & 15;
    const int sp = w / 288;
    const int b = bh >> 2, h = bh & 3;
    const int lane = tid & 63, wv = tid >> 6;
    const int l31 = lane & 31, hi = lane >> 5, l7 = lane & 7;
    const int lrow = lane >> 3, lslot = (lane & 7) ^ lrow;
    const int n0 = qt * 128;
    const size_t ndb = (size_t)(b * HEADS + h) * NN * HD;
    const size_t cnb = ((size_t)b * CCH + h * HD) * NN;

    // staging pointers (pre-swizzled global source, linear LDS dest)
    const char* kgp = (const char*)(Knd + ndb) + (size_t)(sp * 576 + wv * 16 + lrow) * 128 + lslot * 16;
    const char* vgp = (const char*)(Vcn + cnb + sp * 576) + (size_t)(wv * 16 + lrow) * (NN * 2) + lslot * 16;
    char* kls = smem + wv * 2048;
    char* vls = smem + 16384 + wv * 2048;

#define STAGE(buf, t) do { \
    const char* kp_ = kgp + (size_t)(t) * 8192; \
    const char* vp_ = vgp + (size_t)(t) * 128; \
    char* kd_ = kls + (buf) * 8192; \
    char* vd_ = vls + (buf) * 8192; \
    gload16(kp_,              kd_); \
    gload16(kp_ + 1024,       kd_ + 1024); \
    gload16(vp_,              vd_); \
    gload16(vp_ + 8 * (NN*2), vd_ + 1024); \
} while (0)

    // Q B-fragments: 32 q/wave, q = n0 + wv*32 + l31; frag ds covers d=ds*16+hi*8..+7
    bfrag qb[4];
    {
        const ushort_t* qbase = Qnd + ndb + (size_t)(n0 + wv * 32 + l31) * HD + hi * 8;
#pragma unroll
        for (int ds = 0; ds < 4; ++ds)
            qb[ds] = *(const bfrag*)&qbase[ds * 16];
    }
    // fixed softmax bound m0 = |q| * max|k'| + margin (lane holds 32 of 64 d)
    float m0;
    {
        float s = 0.f;
#pragma unroll
        for (int ds = 0; ds < 4; ++ds) {
            const unsigned* uu = (const unsigned*)&qb[ds];
#pragma unroll
            for (int j = 0; j < 4; ++j) {
                float a0 = bflo(uu[j]), a1 = bfhi(uu[j]);
                s += a0*a0 + a1*a1;
            }
        }
        s += __shfl_xor(s, 32);
        m0 = sqrtf(s) * sqrtf(kmax2[bh]) + 0.5f;
    }

    f32x16 o[2];
#pragma unroll
    for (int db = 0; db < 2; ++db)
#pragma unroll
        for (int j = 0; j < 16; ++j) o[db][j] = 0.f;
    float lacc = 0.f;

    STAGE(0, 0);    // tile-0 loads in flight

    for (int t = 0; t < 9; ++t) {
        const int cur = t & 1;
        if (t < 8) {
            STAGE(cur ^ 1, t + 1);                            // prefetch t+1
            asm volatile("s_waitcnt vmcnt(4)" ::: "memory");  // t done, t+1 flying
        } else {
            asm volatile("s_waitcnt vmcnt(0)" ::: "memory");
        }
        __builtin_amdgcn_s_barrier();
        const char* Kb = smem + cur * 8192;
        const char* Vb = smem + 16384 + cur * 8192;

        // QK + softmax + in-register P fragments
        bfrag pf[4];
#pragma unroll
        for (int kb = 0; kb < 2; ++kb) {
            f32x16 s;
#pragma unroll
            for (int j = 0; j < 16; ++j) s[j] = -m0;
            __builtin_amdgcn_s_setprio(1);
#pragma unroll
            for (int ds = 0; ds < 4; ++ds) {
                const char* ka_p = Kb + (kb * 32 + l31) * 128 + (((2 * ds + hi) ^ l7) << 4);
                bfrag ka = *(const bfrag*)ka_p;
                s = MFMA32(ka, qb[ds], s, 0, 0, 0);
            }
            __builtin_amdgcn_s_setprio(0);
            float e[16];
#pragma unroll
            for (int j = 0; j < 16; ++j) { e[j] = exp2f(s[j]); lacc += e[j]; }
            unsigned u[4][2];
#pragma unroll
            for (int g = 0; g < 4; ++g) {
                u[g][0] = cvtpk(e[4 * g + 0], e[4 * g + 1]);
                u[g][1] = cvtpk(e[4 * g + 2], e[4 * g + 3]);
            }
            // half-wave exchange: frag = {X'0, X'1, Y'0, Y'1}
#pragma unroll
            for (int ks = 0; ks < 2; ++ks) {
                asm("v_permlane32_swap_b32 %0, %1" : "+v"(u[2*ks][0]), "+v"(u[2*ks+1][0]));
                asm("v_permlane32_swap_b32 %0, %1" : "+v"(u[2*ks][1]), "+v"(u[2*ks+1][1]));
                uint4 fw = { u[2*ks][0], u[2*ks][1], u[2*ks+1][0], u[2*ks+1][1] };
                pf[kb * 2 + ks] = *(const bfrag*)&fw;
            }
        }

        // PV: O^T[64 d][32 q] += V^T * P^T  (V direct from LDS, P from regs)
        __builtin_amdgcn_s_setprio(1);
#pragma unroll
        for (int db = 0; db < 2; ++db)
#pragma unroll
            for (int ks = 0; ks < 4; ++ks) {
                const char* va_p = Vb + (db * 32 + l31) * 128 + (((2 * ks + hi) ^ l7) << 4);
                bfrag va = *(const bfrag*)va_p;
                o[db] = MFMA32(va, pf[ks], o[db], 0, 0, 0);
            }
        __builtin_amdgcn_s_setprio(0);

        __builtin_amdgcn_s_barrier();    // all waves done reading buf[cur]
    }
#undef STAGE

    // l: in-lane partial + cross-half combine (both halves share q = l31)
    lacc += __shfl_xor(lacc, 32);
    if (hi == 0)
        Larr[(size_t)(sp * 16 + bh) * NN + n0 + wv * 32 + l31] = lacc;

    // epilogue: pack O' bf16, transpose via LDS, coalesced uint4 stores
    unsigned (*Osb)[36] = (unsigned(*)[36])smem;   // [128][36] u32
    {
        int row = wv * 32 + l31;
#pragma unroll
        for (int db = 0; db < 2; ++db)
#pragma unroll
            for (int g = 0; g < 4; ++g) {
                uint2 pk;
                pk.x = cvtpk(o[db][4 * g + 0], o[db][4 * g + 1]);
                pk.y = cvtpk(o[db][4 * g + 2], o[db][4 * g + 3]);
                *(uint2*)&Osb[row][16 * db + 4 * g + 2 * hi] = pk;
            }
    }
    __syncthreads();
    ushort_t* opb = Op + (size_t)sp * BCN + ((size_t)b * NN + n0) * CCH + h * HD;
    for (int idx = tid; idx < 1024; idx += 256) {
        int n = idx >> 3, s4 = idx & 7;
        *(uint4*)&opb[(size_t)n * CCH + s4 * 8] = *(const uint4*)&Osb[n][s4 * 4];
    }
}

// ---------------------------------------------------------------------------
// fuse: sum kv-splits (bf16 O', shared m0) + depthwise 3x3 BN -> bf16 [b][n][c]
// ---------------------------------------------------------------------------
__global__ __launch_bounds__(256)
void fuse_kernel(const ushort_t* __restrict__ Op, const float* __restrict__ Larr,
                 const ushort_t* __restrict__ Qnd,
                 const ushort_t* __restrict__ pw2, const float* __restrict__ pbias,
                 ushort_t* __restrict__ yt)
{
    const int tid = threadIdx.x;
    const int b  = blockIdx.x / 288;
    const int n0 = (blockIdx.x % 288) * 8;
    const int c8 = tid & 31, ns = tid >> 5;
    const int n  = n0 + ns;
    const int h  = c8 >> 3, c0 = c8 * 8;

    const ushort_t* o0p = Op + ((size_t)b * NN + n) * CCH + c0;
    float acc[8] = {0.f, 0.f, 0.f, 0.f, 0.f, 0.f, 0.f, 0.f};
#pragma unroll
    for (int s = 0; s < NSP; ++s) {
        uint4 u = *(const uint4*)&o0p[(size_t)s * BCN];
        acc[0] += bflo(u.x); acc[1] += bfhi(u.x);
        acc[2] += bflo(u.y); acc[3] += bfhi(u.y);
        acc[4] += bflo(u.z); acc[5] += bfhi(u.z);
        acc[6] += bflo(u.w); acc[7] += bfhi(u.w);
    }
    int mi = (b * HEADS + h) * NN + n;
    float ls = 0.f;
#pragma unroll
    for (int s = 0; s < NSP; ++s) ls += Larr[(size_t)s * 16 * NN + mi];
    float rinv = 1.0f / ls;
#pragma unroll
    for (int j = 0; j < 8; ++j) acc[j] *= rinv;

    const int x = n % WW, y = n / WW;
    const ushort_t* qb = Qnd + (size_t)(b * HEADS + h) * NN * HD + (c8 & 7) * 8;
#pragma unroll
    for (int ky = 0; ky < 3; ++ky) {
        int yy = y + ky - 1;
        if (yy < 0 || yy >= HH) continue;
#pragma unroll
        for (int kx = 0; kx < 3; ++kx) {
            int xx = x + kx - 1;
            if (xx < 0 || xx >= WW) continue;
            int np = yy * WW + xx;
            uint4 qv = *(const uint4*)&qb[(size_t)np * HD];
            uint4 w4 = *(const uint4*)&pw2[(ky * 3 + kx) * CCH + c0];
            acc[0] += bflo(qv.x) * bflo(w4.x); acc[1] += bfhi(qv.x) * bfhi(w4.x);
            acc[2] += bflo(qv.y) * bflo(w4.y); acc[3] += bfhi(qv.y) * bfhi(w4.y);
            acc[4] += bflo(qv.z) * bflo(w4.z); acc[5] += bfhi(qv.z) * bfhi(w4.z);
            acc[6] += bflo(qv.w) * bflo(w4.w); acc[7] += bfhi(qv.w) * bfhi(w4.w);
        }
    }
    float4 p0 = *(const float4*)&pbias[c0];
    float4 p1 = *(const float4*)&pbias[c0 + 4];
    acc[0] += p0.x; acc[1] += p0.y; acc[2] += p0.z; acc[3] += p0.w;
    acc[4] += p1.x; acc[5] += p1.y; acc[6] += p1.z; acc[7] += p1.w;
    uint4 u;
    u.x = cvtpk(acc[0], acc[1]); u.y = cvtpk(acc[2], acc[3]);
    u.z = cvtpk(acc[4], acc[5]); u.w = cvtpk(acc[6], acc[7]);
    *(uint4*)&yt[((size_t)b * NN + n) * CCH + c0] = u;
}

// ---------------------------------------------------------------------------
extern "C" void kernel_launch(void* const* d_in, const int* in_sizes, int n_in,
                              void* d_out, int out_size, void* d_ws, size_t ws_size,
                              hipStream_t stream) {
    char* ws = (char*)d_ws;
    ushort_t* qnd  = (ushort_t*)(ws + 0);
    ushort_t* knd  = (ushort_t*)(ws + 4718592);
    ushort_t* vcn  = (ushort_t*)(ws + 9437184);
    ushort_t* Xt   = (ushort_t*)(ws + 14155776);
    ushort_t* Op   = (ushort_t*)(ws + 14155776);   // bf16 [4][BCN], overlays Xt
    ushort_t* yt   = (ushort_t*)(ws + 4718592);    // overlays knd after attn
    float*    Larr = (float*)   (ws + 33030144);   // [4][16][NN] fp32
    ushort_t* W4   = (ushort_t*)(ws + 33619968);
    float*    bias4= (float*)   (ws + 34144256);
    ushort_t* pw2  = (ushort_t*)(ws + 34148352);
    float*    pbias= (float*)   (ws + 34152960);
    float*    kmax2= (float*)   (ws + 34156032);

    PrepWP P;
    P.W[0] = (const float*)d_in[3]; P.W[1] = (const float*)d_in[4];
    P.W[2] = (const float*)d_in[5]; P.W[3] = (const float*)d_in[6];
    P.G[0]  = (const float*)d_in[8];  P.Bb[0] = (const float*)d_in[9];
    P.Mm[0] = (const float*)d_in[10]; P.Vv[0] = (const float*)d_in[11];
    P.G[1]  = (const float*)d_in[12]; P.Bb[1] = (const float*)d_in[13];
    P.Mm[1] = (const float*)d_in[14]; P.Vv[1] = (const float*)d_in[15];
    P.G[2]  = (const float*)d_in[16]; P.Bb[2] = (const float*)d_in[17];
    P.Mm[2] = (const float*)d_in[18]; P.Vv[2] = (const float*)d_in[19];
    P.G[3]  = (const float*)d_in[24]; P.Bb[3] = (const float*)d_in[25];
    P.Mm[3] = (const float*)d_in[26]; P.Vv[3] = (const float*)d_in[27];
    P.pew = (const float*)d_in[7];
    P.peg = (const float*)d_in[20]; P.peb = (const float*)d_in[21];
    P.pem = (const float*)d_in[22]; P.pev = (const float*)d_in[23];
    P.W4 = W4; P.bias4 = bias4; P.pw2 = pw2; P.pbias = pbias; P.kmax2 = kmax2;
    P.q = (const float*)d_in[0]; P.k = (const float*)d_in[1];
    P.v = (const float*)d_in[2]; P.Xt = Xt;

    prep_kernel<<<3585, 256, 0, stream>>>(P);

    conv_gemm<0><<<dim3(36, 4, 12), 256, 0, stream>>>(Xt, W4, bias4, qnd, knd, vcn, nullptr, kmax2);

    attn_kernel<<<dim3(18, 16, NSP), 256, 0, stream>>>(qnd, knd, vcn, kmax2, Op, Larr);

    fuse_kernel<<<1152, 256, 0, stream>>>(Op, Larr, qnd, pw2, pbias, yt);

    conv_gemm<1><<<dim3(36, 4, 4), 256, 0, stream>>>(yt, W4, bias4, nullptr, nullptr, nullptr,
                                                     (float*)d_out, nullptr);
}

// Round 14
// 81.863 us; speedup vs baseline: 1.2656x; 1.1197x over previous
//
#include <hip/hip_runtime.h>
#include <math.h>

#define HEADS 4
#define HD    64
#define CCH   256
#define NB    4
#define HH    48
#define WW    48
#define NN    (HH*WW)            // 2304
#define EPSBN 1e-5f
#define KSCL  0.18033688f        // 0.125 * log2(e)  (folded into K weights/bias)
#define BCN   (NB*CCH*NN)        // 2,359,296 elements
#define NSP   4                  // kv splits

typedef unsigned short ushort_t;
typedef __attribute__((ext_vector_type(8))) short bfrag;    // 8 bf16 = 4 VGPR
typedef __attribute__((ext_vector_type(4))) float f32x4;    // 16x16 C/D
typedef __attribute__((ext_vector_type(16))) float f32x16;  // 32x32 C/D

#define MFMA   __builtin_amdgcn_mfma_f32_16x16x32_bf16
#define MFMA32 __builtin_amdgcn_mfma_f32_32x32x16_bf16

static __device__ __forceinline__ ushort_t f2bf(float x) {
    unsigned int u = __float_as_uint(x);
    unsigned int r = (u + 0x7fffu + ((u >> 16) & 1u)) >> 16;   // RNE
    return (ushort_t)r;
}
static __device__ __forceinline__ unsigned cvtpk(float lo, float hi) {
    unsigned r;
    asm("v_cvt_pk_bf16_f32 %0, %1, %2" : "=v"(r) : "v"(lo), "v"(hi));
    return r;
}
static __device__ __forceinline__ float bflo(unsigned u) { return __uint_as_float(u << 16); }
static __device__ __forceinline__ float bfhi(unsigned u) { return __uint_as_float(u & 0xffff0000u); }

static __device__ __forceinline__ void gload16(const void* g, void* l) {
    __builtin_amdgcn_global_load_lds(
        (const __attribute__((address_space(1))) void*)g,
        (__attribute__((address_space(3))) void*)l, 16, 0, 0);
}

// ---------------------------------------------------------------------------
// prep: fold BN into weights -> bf16 W'[4][256][256], bias'[4][256];
// pe weights tap-major bf16. (q/k/v transpose now lives inside conv_gemm.)
// ---------------------------------------------------------------------------
struct PrepWP {
    const float* W[4];
    const float* G[4]; const float* Bb[4]; const float* Mm[4]; const float* Vv[4];
    const float* pew; const float* peg; const float* peb; const float* pem; const float* pev;
    ushort_t* W4; float* bias4; ushort_t* pw2; float* pbias;
};
__global__ __launch_bounds__(256)
void prep_w(PrepWP P)
{
    const int blk = blockIdx.x, tid = threadIdx.x;
    if (blk == 128) {
        int c = tid;
        float s = P.peg[c] * rsqrtf(P.pev[c] + EPSBN);
        for (int tap = 0; tap < 9; ++tap)
            P.pw2[tap * CCH + c] = f2bf(P.pew[c * 9 + tap] * s);
        P.pbias[c] = P.peb[c] - P.pem[c] * s;
        return;
    }
    int g  = blk * 256 + tid;
    int cv = g >> 13;
    int o  = (g >> 5) & 255;
    int c8 = g & 31;
    float s  = P.G[cv][o] * rsqrtf(P.Vv[cv][o] + EPSBN);
    float s2 = (cv == 1) ? s * KSCL : s;
    const float* w = P.W[cv] + (size_t)o * CCH + c8 * 8;
    uint4 u;
    u.x = cvtpk(w[0]*s2, w[1]*s2); u.y = cvtpk(w[2]*s2, w[3]*s2);
    u.z = cvtpk(w[4]*s2, w[5]*s2); u.w = cvtpk(w[6]*s2, w[7]*s2);
    *(uint4*)&P.W4[((size_t)cv * CCH + o) * CCH + c8 * 8] = u;
    if (c8 == 0) {
        float bb = (P.Bb[cv][o] - P.Mm[cv][o] * s);
        P.bias4[cv * CCH + o] = (cv == 1) ? bb * KSCL : bb;
    }
}

// ---------------------------------------------------------------------------
// bf16 MFMA 1x1-conv GEMM, 64x64 tile, full K=256 staged once.
// MODE 0 (q/k/v): stages T directly from fp32 [b][c][n] inputs with in-LDS
//   transpose+bf16 convert (prep pass eliminated). which = z>>2:
//   0(q),1(k) -> bf16 [b][h][n][d]; 2(v) -> bf16 [b][c][n].
// MODE 1 (proj): T = yt bf16 [b][n][c]; fp32 [b][c][n] -> d_out.
// ---------------------------------------------------------------------------
template<int PROJ>
__global__ __launch_bounds__(256)
void conv_gemm(const float* __restrict__ qf, const float* __restrict__ kf,
               const float* __restrict__ vf, const ushort_t* __restrict__ T,
               const ushort_t* __restrict__ W4, const float* __restrict__ bias4,
               ushort_t* __restrict__ qnd, ushort_t* __restrict__ knd,
               ushort_t* __restrict__ vcn, float* __restrict__ outf)
{
    __shared__ ushort_t Ts[64][264];
    __shared__ ushort_t Ws[64][264];
    const int nt = blockIdx.x, ot = blockIdx.y, z = blockIdx.z;
    const int which = PROJ ? 3 : (z >> 2);
    const int b = z & 3;
    const int tid = threadIdx.x;
    const int n0 = nt * 64, o0 = ot * 64;
    const ushort_t* Wsrc = W4 + (size_t)which * CCH * CCH + (size_t)o0 * CCH;
    const float*    bias = bias4 + which * CCH;

    if (!PROJ) {
        // Ws: bf16 rows, coalesced
#pragma unroll
        for (int i = 0; i < 8; ++i) {
            int idx = tid + i * 256;
            int r = idx >> 5, c16 = idx & 31;
            *(uint4*)&Ws[r][c16 * 8] = *(const uint4*)&Wsrc[(size_t)r * CCH + c16 * 8];
        }
        // Ts: fp32 [c][n] -> bf16 [n][c] transpose (8 passes)
        const float* Xf = (which == 0) ? qf : (which == 1) ? kf : vf;
        const float* Xb = Xf + (size_t)b * CCH * NN + n0;
        const int n = tid & 63;
#pragma unroll
        for (int p = 0; p < 8; ++p) {
            int c0 = (tid >> 6) * 8 + p * 32;
            const float* src = Xb + (size_t)c0 * NN + n;
            float vv[8];
#pragma unroll
            for (int j = 0; j < 8; ++j) vv[j] = src[(size_t)j * NN];
            uint4 u;
            u.x = cvtpk(vv[0], vv[1]); u.y = cvtpk(vv[2], vv[3]);
            u.z = cvtpk(vv[4], vv[5]); u.w = cvtpk(vv[6], vv[7]);
            *(uint4*)&Ts[n][c0] = u;
        }
    } else {
        const ushort_t* Tsrc = T + ((size_t)b * NN + n0) * CCH;
#pragma unroll
        for (int i = 0; i < 8; ++i) {
            int idx = tid + i * 256;
            int r = idx >> 5, c16 = idx & 31;
            *(uint4*)&Ts[r][c16 * 8] = *(const uint4*)&Tsrc[(size_t)r * CCH + c16 * 8];
            *(uint4*)&Ws[r][c16 * 8] = *(const uint4*)&Wsrc[(size_t)r * CCH + c16 * 8];
        }
    }
    __syncthreads();
    const int wv = tid >> 6, lane = tid & 63, lr = lane & 15, lg = lane >> 4;
    const int qn = (wv >> 1) * 32, qo = (wv & 1) * 32;
    f32x4 acc[2][2];
#pragma unroll
    for (int i = 0; i < 2; ++i)
#pragma unroll
        for (int j = 0; j < 2; ++j) acc[i][j] = (f32x4){0.f, 0.f, 0.f, 0.f};

    if (!PROJ && (z >> 2) < 2) {
#pragma unroll
        for (int k8 = 0; k8 < 8; ++k8) {
            const int kc = k8 * 32 + lg * 8;
            bfrag ta0 = *(const bfrag*)&Ts[qn + lr][kc];
            bfrag ta1 = *(const bfrag*)&Ts[qn + 16 + lr][kc];
            bfrag wa0 = *(const bfrag*)&Ws[qo + lr][kc];
            bfrag wa1 = *(const bfrag*)&Ws[qo + 16 + lr][kc];
            acc[0][0] = MFMA(ta0, wa0, acc[0][0], 0, 0, 0);
            acc[0][1] = MFMA(ta0, wa1, acc[0][1], 0, 0, 0);
            acc[1][0] = MFMA(ta1, wa0, acc[1][0], 0, 0, 0);
            acc[1][1] = MFMA(ta1, wa1, acc[1][1], 0, 0, 0);
        }
    } else {
#pragma unroll
        for (int k8 = 0; k8 < 8; ++k8) {
            const int kc = k8 * 32 + lg * 8;
            bfrag ta0 = *(const bfrag*)&Ts[qn + lr][kc];
            bfrag ta1 = *(const bfrag*)&Ts[qn + 16 + lr][kc];
            bfrag wa0 = *(const bfrag*)&Ws[qo + lr][kc];
            bfrag wa1 = *(const bfrag*)&Ws[qo + 16 + lr][kc];
            acc[0][0] = MFMA(wa0, ta0, acc[0][0], 0, 0, 0);
            acc[0][1] = MFMA(wa0, ta1, acc[0][1], 0, 0, 0);
            acc[1][0] = MFMA(wa1, ta0, acc[1][0], 0, 0, 0);
            acc[1][1] = MFMA(wa1, ta1, acc[1][1], 0, 0, 0);
        }
    }

    __syncthreads();   // Ts/Ws dead; overlay epilogue staging
    if (!PROJ && which < 2) {
        ushort_t (*Ot)[72] = (ushort_t(*)[72])Ts;
        float bv[2] = { bias[o0 + qo + lr], bias[o0 + qo + 16 + lr] };
#pragma unroll
        for (int i = 0; i < 2; ++i)
#pragma unroll
            for (int j = 0; j < 2; ++j)
#pragma unroll
                for (int r = 0; r < 4; ++r)
                    Ot[qn + i * 16 + lg * 4 + r][qo + j * 16 + lr] = f2bf(acc[i][j][r] + bv[j]);
        __syncthreads();
        ushort_t* out = (which == 0) ? qnd : knd;
        for (int idx = tid; idx < 512; idx += 256) {
            int r = idx >> 3, sg = idx & 7;
            *(uint4*)&out[(((size_t)b * HEADS + ot) * NN + n0 + r) * HD + sg * 8] =
                *(const uint4*)&Ot[r][sg * 8];
        }
    } else if (!PROJ) {
        ushort_t (*Ot)[72] = (ushort_t(*)[72])Ts;
#pragma unroll
        for (int i = 0; i < 2; ++i)
#pragma unroll
            for (int r = 0; r < 4; ++r) {
                float bv = bias[o0 + qo + i * 16 + lg * 4 + r];
#pragma unroll
                for (int j = 0; j < 2; ++j)
                    Ot[qo + i * 16 + lg * 4 + r][qn + j * 16 + lr] = f2bf(acc[i][j][r] + bv);
            }
        __syncthreads();
        for (int idx = tid; idx < 512; idx += 256) {
            int r = idx >> 3, sg = idx & 7;
            *(uint4*)&vcn[((size_t)b * CCH + o0 + r) * NN + n0 + sg * 8] =
                *(const uint4*)&Ot[r][sg * 8];
        }
    } else {
        float (*Of)[68] = (float(*)[68])Ts;
#pragma unroll
        for (int i = 0; i < 2; ++i)
#pragma unroll
            for (int r = 0; r < 4; ++r) {
                float bv = bias[o0 + qo + i * 16 + lg * 4 + r];
#pragma unroll
                for (int j = 0; j < 2; ++j)
                    Of[qo + i * 16 + lg * 4 + r][qn + j * 16 + lr] = acc[i][j][r] + bv;
            }
        __syncthreads();
        for (int idx = tid; idx < 1024; idx += 256) {
            int r = idx >> 4, c4 = idx & 15;
            *(float4*)&outf[((size_t)b * CCH + o0 + r) * NN + n0 + c4 * 4] =
                *(const float4*)&Of[r][c4 * 4];
        }
    }
}

// ---------------------------------------------------------------------------
// MFMA flash attention, 32x32x16 shape: 4 waves x 32 q, Bc=64, kv-split x4.
// No softmax shift at all: p = exp2(s) raw (shift cancels in O/l; s bounded
// far below fp32 overflow). P in registers via cvt_pk + v_permlane32_swap.
// LDS 32KB = K dbuf + V dbuf. Counted-vmcnt 2-barrier pipeline.
// ---------------------------------------------------------------------------
__global__ __launch_bounds__(256, 4)
void attn_kernel(const ushort_t* __restrict__ Qnd,   // bf16 [b][h][n][d]
                 const ushort_t* __restrict__ Knd,   // bf16 [b][h][n][d] *KSCL
                 const ushort_t* __restrict__ Vcn,   // bf16 [b][c][n]
                 ushort_t* __restrict__ Op,          // bf16 [4][b][n][c]
                 float* __restrict__ Larr)           // fp32 [4][16][NN]
{
    __shared__ __align__(16) char smem[32768];

    const int tid = threadIdx.x;
    const int lin0 = blockIdx.x + 18 * blockIdx.y + 288 * blockIdx.z;
    const int w    = (lin0 & 7) * 144 + (lin0 >> 3);   // XCD-chunked remap (1152=8*144)
    const int qt = w % 18;
    const int bh = (w / 18) & 15;
    const int sp = w / 288;
    const int b = bh >> 2, h = bh & 3;
    const int lane = tid & 63, wv = tid >> 6;
    const int l31 = lane & 31, hi = lane >> 5, l7 = lane & 7;
    const int lrow = lane >> 3, lslot = (lane & 7) ^ lrow;
    const int n0 = qt * 128;
    const size_t ndb = (size_t)(b * HEADS + h) * NN * HD;
    const size_t cnb = ((size_t)b * CCH + h * HD) * NN;

    const char* kgp = (const char*)(Knd + ndb) + (size_t)(sp * 576 + wv * 16 + lrow) * 128 + lslot * 16;
    const char* vgp = (const char*)(Vcn + cnb + sp * 576) + (size_t)(wv * 16 + lrow) * (NN * 2) + lslot * 16;
    char* kls = smem + wv * 2048;
    char* vls = smem + 16384 + wv * 2048;

#define STAGE(buf, t) do { \
    const char* kp_ = kgp + (size_t)(t) * 8192; \
    const char* vp_ = vgp + (size_t)(t) * 128; \
    char* kd_ = kls + (buf) * 8192; \
    char* vd_ = vls + (buf) * 8192; \
    gload16(kp_,              kd_); \
    gload16(kp_ + 1024,       kd_ + 1024); \
    gload16(vp_,              vd_); \
    gload16(vp_ + 8 * (NN*2), vd_ + 1024); \
} while (0)

    // Q B-fragments: 32 q/wave, q = n0 + wv*32 + l31; frag ds covers d=ds*16+hi*8..+7
    bfrag qb[4];
    {
        const ushort_t* qbase = Qnd + ndb + (size_t)(n0 + wv * 32 + l31) * HD + hi * 8;
#pragma unroll
        for (int ds = 0; ds < 4; ++ds)
            qb[ds] = *(const bfrag*)&qbase[ds * 16];
    }

    f32x16 o[2];
#pragma unroll
    for (int db = 0; db < 2; ++db)
#pragma unroll
        for (int j = 0; j < 16; ++j) o[db][j] = 0.f;
    float lacc = 0.f;

    STAGE(0, 0);

    for (int t = 0; t < 9; ++t) {
        const int cur = t & 1;
        if (t < 8) {
            STAGE(cur ^ 1, t + 1);                            // prefetch t+1
            asm volatile("s_waitcnt vmcnt(4)" ::: "memory");  // t done, t+1 flying
        } else {
            asm volatile("s_waitcnt vmcnt(0)" ::: "memory");
        }
        __builtin_amdgcn_s_barrier();
        const char* Kb = smem + cur * 8192;
        const char* Vb = smem + 16384 + cur * 8192;

        // QK + raw exp2 + in-register P fragments
        bfrag pf[4];
#pragma unroll
        for (int kb = 0; kb < 2; ++kb) {
            f32x16 s;
#pragma unroll
            for (int j = 0; j < 16; ++j) s[j] = 0.f;
            __builtin_amdgcn_s_setprio(1);
#pragma unroll
            for (int ds = 0; ds < 4; ++ds) {
                const char* ka_p = Kb + (kb * 32 + l31) * 128 + (((2 * ds + hi) ^ l7) << 4);
                bfrag ka = *(const bfrag*)ka_p;
                s = MFMA32(ka, qb[ds], s, 0, 0, 0);
            }
            __builtin_amdgcn_s_setprio(0);
            float e[16];
#pragma unroll
            for (int j = 0; j < 16; ++j) { e[j] = exp2f(s[j]); lacc += e[j]; }
            unsigned u[4][2];
#pragma unroll
            for (int g = 0; g < 4; ++g) {
                u[g][0] = cvtpk(e[4 * g + 0], e[4 * g + 1]);
                u[g][1] = cvtpk(e[4 * g + 2], e[4 * g + 3]);
            }
#pragma unroll
            for (int ks = 0; ks < 2; ++ks) {
                asm("v_permlane32_swap_b32 %0, %1" : "+v"(u[2*ks][0]), "+v"(u[2*ks+1][0]));
                asm("v_permlane32_swap_b32 %0, %1" : "+v"(u[2*ks][1]), "+v"(u[2*ks+1][1]));
                uint4 fw = { u[2*ks][0], u[2*ks][1], u[2*ks+1][0], u[2*ks+1][1] };
                pf[kb * 2 + ks] = *(const bfrag*)&fw;
            }
        }

        // PV: O^T[64 d][32 q] += V^T * P^T
        __builtin_amdgcn_s_setprio(1);
#pragma unroll
        for (int db = 0; db < 2; ++db)
#pragma unroll
            for (int ks = 0; ks < 4; ++ks) {
                const char* va_p = Vb + (db * 32 + l31) * 128 + (((2 * ks + hi) ^ l7) << 4);
                bfrag va = *(const bfrag*)va_p;
                o[db] = MFMA32(va, pf[ks], o[db], 0, 0, 0);
            }
        __builtin_amdgcn_s_setprio(0);

        __builtin_amdgcn_s_barrier();
    }
#undef STAGE

    // l: in-lane partial + cross-half combine (both halves share q = l31)
    lacc += __shfl_xor(lacc, 32);
    if (hi == 0)
        Larr[(size_t)(sp * 16 + bh) * NN + n0 + wv * 32 + l31] = lacc;

    // epilogue: pack O' bf16, transpose via LDS, coalesced uint4 stores
    unsigned (*Osb)[36] = (unsigned(*)[36])smem;   // [128][36] u32
    {
        int row = wv * 32 + l31;
#pragma unroll
        for (int db = 0; db < 2; ++db)
#pragma unroll
            for (int g = 0; g < 4; ++g) {
                uint2 pk;
                pk.x = cvtpk(o[db][4 * g + 0], o[db][4 * g + 1]);
                pk.y = cvtpk(o[db][4 * g + 2], o[db][4 * g + 3]);
                *(uint2*)&Osb[row][16 * db + 4 * g + 2 * hi] = pk;
            }
    }
    __syncthreads();
    ushort_t* opb = Op + (size_t)sp * BCN + ((size_t)b * NN + n0) * CCH + h * HD;
    for (int idx = tid; idx < 1024; idx += 256) {
        int n = idx >> 3, s4 = idx & 7;
        *(uint4*)&opb[(size_t)n * CCH + s4 * 8] = *(const uint4*)&Osb[n][s4 * 4];
    }
}

// ---------------------------------------------------------------------------
// fuse: sum kv-splits (bf16 O') + depthwise 3x3 BN -> bf16 [b][n][c]
// ---------------------------------------------------------------------------
__global__ __launch_bounds__(256)
void fuse_kernel(const ushort_t* __restrict__ Op, const float* __restrict__ Larr,
                 const ushort_t* __restrict__ Qnd,
                 const ushort_t* __restrict__ pw2, const float* __restrict__ pbias,
                 ushort_t* __restrict__ yt)
{
    const int tid = threadIdx.x;
    const int b  = blockIdx.x / 288;
    const int n0 = (blockIdx.x % 288) * 8;
    const int c8 = tid & 31, ns = tid >> 5;
    const int n  = n0 + ns;
    const int h  = c8 >> 3, c0 = c8 * 8;

    const ushort_t* o0p = Op + ((size_t)b * NN + n) * CCH + c0;
    float acc[8] = {0.f, 0.f, 0.f, 0.f, 0.f, 0.f, 0.f, 0.f};
#pragma unroll
    for (int s = 0; s < NSP; ++s) {
        uint4 u = *(const uint4*)&o0p[(size_t)s * BCN];
        acc[0] += bflo(u.x); acc[1] += bfhi(u.x);
        acc[2] += bflo(u.y); acc[3] += bfhi(u.y);
        acc[4] += bflo(u.z); acc[5] += bfhi(u.z);
        acc[6] += bflo(u.w); acc[7] += bfhi(u.w);
    }
    int mi = (b * HEADS + h) * NN + n;
    float ls = 0.f;
#pragma unroll
    for (int s = 0; s < NSP; ++s) ls += Larr[(size_t)s * 16 * NN + mi];
    float rinv = 1.0f / ls;
#pragma unroll
    for (int j = 0; j < 8; ++j) acc[j] *= rinv;

    const int x = n % WW, y = n / WW;
    const ushort_t* qb = Qnd + (size_t)(b * HEADS + h) * NN * HD + (c8 & 7) * 8;
#pragma unroll
    for (int ky = 0; ky < 3; ++ky) {
        int yy = y + ky - 1;
        if (yy < 0 || yy >= HH) continue;
#pragma unroll
        for (int kx = 0; kx < 3; ++kx) {
            int xx = x + kx - 1;
            if (xx < 0 || xx >= WW) continue;
            int np = yy * WW + xx;
            uint4 qv = *(const uint4*)&qb[(size_t)np * HD];
            uint4 w4 = *(const uint4*)&pw2[(ky * 3 + kx) * CCH + c0];
            acc[0] += bflo(qv.x) * bflo(w4.x); acc[1] += bfhi(qv.x) * bfhi(w4.x);
            acc[2] += bflo(qv.y) * bflo(w4.y); acc[3] += bfhi(qv.y) * bfhi(w4.y);
            acc[4] += bflo(qv.z) * bflo(w4.z); acc[5] += bfhi(qv.z) * bfhi(w4.z);
            acc[6] += bflo(qv.w) * bflo(w4.w); acc[7] += bfhi(qv.w) * bfhi(w4.w);
        }
    }
    float4 p0 = *(const float4*)&pbias[c0];
    float4 p1 = *(const float4*)&pbias[c0 + 4];
    acc[0] += p0.x; acc[1] += p0.y; acc[2] += p0.z; acc[3] += p0.w;
    acc[4] += p1.x; acc[5] += p1.y; acc[6] += p1.z; acc[7] += p1.w;
    uint4 u;
    u.x = cvtpk(acc[0], acc[1]); u.y = cvtpk(acc[2], acc[3]);
    u.z = cvtpk(acc[4], acc[5]); u.w = cvtpk(acc[6], acc[7]);
    *(uint4*)&yt[((size_t)b * NN + n) * CCH + c0] = u;
}

// ---------------------------------------------------------------------------
extern "C" void kernel_launch(void* const* d_in, const int* in_sizes, int n_in,
                              void* d_out, int out_size, void* d_ws, size_t ws_size,
                              hipStream_t stream) {
    const float* q = (const float*)d_in[0];
    const float* k = (const float*)d_in[1];
    const float* v = (const float*)d_in[2];

    char* ws = (char*)d_ws;
    ushort_t* qnd  = (ushort_t*)(ws + 0);
    ushort_t* knd  = (ushort_t*)(ws + 4718592);
    ushort_t* vcn  = (ushort_t*)(ws + 9437184);
    ushort_t* Op   = (ushort_t*)(ws + 14155776);   // bf16 [4][BCN]
    ushort_t* yt   = (ushort_t*)(ws + 4718592);    // overlays knd after attn
    float*    Larr = (float*)   (ws + 33030144);   // [4][16][NN] fp32
    ushort_t* W4   = (ushort_t*)(ws + 33619968);
    float*    bias4= (float*)   (ws + 34144256);
    ushort_t* pw2  = (ushort_t*)(ws + 34148352);
    float*    pbias= (float*)   (ws + 34152960);

    PrepWP P;
    P.W[0] = (const float*)d_in[3]; P.W[1] = (const float*)d_in[4];
    P.W[2] = (const float*)d_in[5]; P.W[3] = (const float*)d_in[6];
    P.G[0]  = (const float*)d_in[8];  P.Bb[0] = (const float*)d_in[9];
    P.Mm[0] = (const float*)d_in[10]; P.Vv[0] = (const float*)d_in[11];
    P.G[1]  = (const float*)d_in[12]; P.Bb[1] = (const float*)d_in[13];
    P.Mm[1] = (const float*)d_in[14]; P.Vv[1] = (const float*)d_in[15];
    P.G[2]  = (const float*)d_in[16]; P.Bb[2] = (const float*)d_in[17];
    P.Mm[2] = (const float*)d_in[18]; P.Vv[2] = (const float*)d_in[19];
    P.G[3]  = (const float*)d_in[24]; P.Bb[3] = (const float*)d_in[25];
    P.Mm[3] = (const float*)d_in[26]; P.Vv[3] = (const float*)d_in[27];
    P.pew = (const float*)d_in[7];
    P.peg = (const float*)d_in[20]; P.peb = (const float*)d_in[21];
    P.pem = (const float*)d_in[22]; P.pev = (const float*)d_in[23];
    P.W4 = W4; P.bias4 = bias4; P.pw2 = pw2; P.pbias = pbias;

    prep_w<<<129, 256, 0, stream>>>(P);

    conv_gemm<0><<<dim3(36, 4, 12), 256, 0, stream>>>(q, k, v, nullptr, W4, bias4,
                                                      qnd, knd, vcn, nullptr);

    attn_kernel<<<dim3(18, 16, NSP), 256, 0, stream>>>(qnd, knd, vcn, Op, Larr);

    fuse_kernel<<<1152, 256, 0, stream>>>(Op, Larr, qnd, pw2, pbias, yt);

    conv_gemm<1><<<dim3(36, 4, 4), 256, 0, stream>>>(nullptr, nullptr, nullptr, yt, W4, bias4,
                                                     nullptr, nullptr, nullptr, (float*)d_out);
}

// Round 15
// 76.111 us; speedup vs baseline: 1.3612x; 1.0756x over previous
//
#include <hip/hip_runtime.h>
#include <math.h>

#define HEADS 4
#define HD    64
#define CCH   256
#define NB    4
#define HH    48
#define WW    48
#define NN    (HH*WW)            // 2304
#define EPSBN 1e-5f
#define KSCL  0.18033688f        // 0.125 * log2(e)  (folded into K weights/bias)
#define BCN   (NB*CCH*NN)        // 2,359,296 elements
#define NSP   4                  // kv splits

typedef unsigned short ushort_t;
typedef __attribute__((ext_vector_type(8))) short bfrag;    // 8 bf16 = 4 VGPR
typedef __attribute__((ext_vector_type(4))) float f32x4;    // 16x16 C/D
typedef __attribute__((ext_vector_type(16))) float f32x16;  // 32x32 C/D

#define MFMA   __builtin_amdgcn_mfma_f32_16x16x32_bf16
#define MFMA32 __builtin_amdgcn_mfma_f32_32x32x16_bf16

static __device__ __forceinline__ ushort_t f2bf(float x) {
    unsigned int u = __float_as_uint(x);
    unsigned int r = (u + 0x7fffu + ((u >> 16) & 1u)) >> 16;   // RNE
    return (ushort_t)r;
}
static __device__ __forceinline__ unsigned cvtpk(float lo, float hi) {
    unsigned r;
    asm("v_cvt_pk_bf16_f32 %0, %1, %2" : "=v"(r) : "v"(lo), "v"(hi));
    return r;
}
static __device__ __forceinline__ float fexp2(float x) {
    // raw v_exp_f32: safe here (|s| <= ~46 << 126; denormal flush harmless)
    float r;
    asm("v_exp_f32 %0, %1" : "=v"(r) : "v"(x));
    return r;
}
static __device__ __forceinline__ float bflo(unsigned u) { return __uint_as_float(u << 16); }
static __device__ __forceinline__ float bfhi(unsigned u) { return __uint_as_float(u & 0xffff0000u); }

static __device__ __forceinline__ void gload16(const void* g, void* l) {
    __builtin_amdgcn_global_load_lds(
        (const __attribute__((address_space(1))) void*)g,
        (__attribute__((address_space(3))) void*)l, 16, 0, 0);
}

// ---------------------------------------------------------------------------
// prep: fold BN into weights -> bf16 W'[4][256][256], bias'[4][256];
// pe weights tap-major bf16. (q/k/v transpose lives inside conv_gemm.)
// ---------------------------------------------------------------------------
struct PrepWP {
    const float* W[4];
    const float* G[4]; const float* Bb[4]; const float* Mm[4]; const float* Vv[4];
    const float* pew; const float* peg; const float* peb; const float* pem; const float* pev;
    ushort_t* W4; float* bias4; ushort_t* pw2; float* pbias;
};
__global__ __launch_bounds__(256)
void prep_w(PrepWP P)
{
    const int blk = blockIdx.x, tid = threadIdx.x;
    if (blk == 128) {
        int c = tid;
        float s = P.peg[c] * rsqrtf(P.pev[c] + EPSBN);
        for (int tap = 0; tap < 9; ++tap)
            P.pw2[tap * CCH + c] = f2bf(P.pew[c * 9 + tap] * s);
        P.pbias[c] = P.peb[c] - P.pem[c] * s;
        return;
    }
    int g  = blk * 256 + tid;
    int cv = g >> 13;
    int o  = (g >> 5) & 255;
    int c8 = g & 31;
    float s  = P.G[cv][o] * rsqrtf(P.Vv[cv][o] + EPSBN);
    float s2 = (cv == 1) ? s * KSCL : s;
    const float* w = P.W[cv] + (size_t)o * CCH + c8 * 8;
    uint4 u;
    u.x = cvtpk(w[0]*s2, w[1]*s2); u.y = cvtpk(w[2]*s2, w[3]*s2);
    u.z = cvtpk(w[4]*s2, w[5]*s2); u.w = cvtpk(w[6]*s2, w[7]*s2);
    *(uint4*)&P.W4[((size_t)cv * CCH + o) * CCH + c8 * 8] = u;
    if (c8 == 0) {
        float bb = (P.Bb[cv][o] - P.Mm[cv][o] * s);
        P.bias4[cv * CCH + o] = (cv == 1) ? bb * KSCL : bb;
    }
}

// ---------------------------------------------------------------------------
// bf16 MFMA 1x1-conv GEMM, 64x64 tile, full K=256 staged once.
// MODE 0 (q/k/v): stages T directly from fp32 [b][c][n] inputs with in-LDS
//   transpose+bf16 convert. which = z>>2: 0(q),1(k) -> bf16 [b][h][n][d];
//   2(v) -> bf16 [b][c][n].
// MODE 1 (proj): T = yt bf16 [b][n][c]; fp32 [b][c][n] -> d_out.
// ---------------------------------------------------------------------------
template<int PROJ>
__global__ __launch_bounds__(256)
void conv_gemm(const float* __restrict__ qf, const float* __restrict__ kf,
               const float* __restrict__ vf, const ushort_t* __restrict__ T,
               const ushort_t* __restrict__ W4, const float* __restrict__ bias4,
               ushort_t* __restrict__ qnd, ushort_t* __restrict__ knd,
               ushort_t* __restrict__ vcn, float* __restrict__ outf)
{
    __shared__ ushort_t Ts[64][264];
    __shared__ ushort_t Ws[64][264];
    const int nt = blockIdx.x, ot = blockIdx.y, z = blockIdx.z;
    const int which = PROJ ? 3 : (z >> 2);
    const int b = z & 3;
    const int tid = threadIdx.x;
    const int n0 = nt * 64, o0 = ot * 64;
    const ushort_t* Wsrc = W4 + (size_t)which * CCH * CCH + (size_t)o0 * CCH;
    const float*    bias = bias4 + which * CCH;

    if (!PROJ) {
#pragma unroll
        for (int i = 0; i < 8; ++i) {
            int idx = tid + i * 256;
            int r = idx >> 5, c16 = idx & 31;
            *(uint4*)&Ws[r][c16 * 8] = *(const uint4*)&Wsrc[(size_t)r * CCH + c16 * 8];
        }
        const float* Xf = (which == 0) ? qf : (which == 1) ? kf : vf;
        const float* Xb = Xf + (size_t)b * CCH * NN + n0;
        const int n = tid & 63;
#pragma unroll
        for (int p = 0; p < 8; ++p) {
            int c0 = (tid >> 6) * 8 + p * 32;
            const float* src = Xb + (size_t)c0 * NN + n;
            float vv[8];
#pragma unroll
            for (int j = 0; j < 8; ++j) vv[j] = src[(size_t)j * NN];
            uint4 u;
            u.x = cvtpk(vv[0], vv[1]); u.y = cvtpk(vv[2], vv[3]);
            u.z = cvtpk(vv[4], vv[5]); u.w = cvtpk(vv[6], vv[7]);
            *(uint4*)&Ts[n][c0] = u;
        }
    } else {
        const ushort_t* Tsrc = T + ((size_t)b * NN + n0) * CCH;
#pragma unroll
        for (int i = 0; i < 8; ++i) {
            int idx = tid + i * 256;
            int r = idx >> 5, c16 = idx & 31;
            *(uint4*)&Ts[r][c16 * 8] = *(const uint4*)&Tsrc[(size_t)r * CCH + c16 * 8];
            *(uint4*)&Ws[r][c16 * 8] = *(const uint4*)&Wsrc[(size_t)r * CCH + c16 * 8];
        }
    }
    __syncthreads();
    const int wv = tid >> 6, lane = tid & 63, lr = lane & 15, lg = lane >> 4;
    const int qn = (wv >> 1) * 32, qo = (wv & 1) * 32;
    f32x4 acc[2][2];
#pragma unroll
    for (int i = 0; i < 2; ++i)
#pragma unroll
        for (int j = 0; j < 2; ++j) acc[i][j] = (f32x4){0.f, 0.f, 0.f, 0.f};

    if (!PROJ && (z >> 2) < 2) {
#pragma unroll
        for (int k8 = 0; k8 < 8; ++k8) {
            const int kc = k8 * 32 + lg * 8;
            bfrag ta0 = *(const bfrag*)&Ts[qn + lr][kc];
            bfrag ta1 = *(const bfrag*)&Ts[qn + 16 + lr][kc];
            bfrag wa0 = *(const bfrag*)&Ws[qo + lr][kc];
            bfrag wa1 = *(const bfrag*)&Ws[qo + 16 + lr][kc];
            acc[0][0] = MFMA(ta0, wa0, acc[0][0], 0, 0, 0);
            acc[0][1] = MFMA(ta0, wa1, acc[0][1], 0, 0, 0);
            acc[1][0] = MFMA(ta1, wa0, acc[1][0], 0, 0, 0);
            acc[1][1] = MFMA(ta1, wa1, acc[1][1], 0, 0, 0);
        }
    } else {
#pragma unroll
        for (int k8 = 0; k8 < 8; ++k8) {
            const int kc = k8 * 32 + lg * 8;
            bfrag ta0 = *(const bfrag*)&Ts[qn + lr][kc];
            bfrag ta1 = *(const bfrag*)&Ts[qn + 16 + lr][kc];
            bfrag wa0 = *(const bfrag*)&Ws[qo + lr][kc];
            bfrag wa1 = *(const bfrag*)&Ws[qo + 16 + lr][kc];
            acc[0][0] = MFMA(wa0, ta0, acc[0][0], 0, 0, 0);
            acc[0][1] = MFMA(wa0, ta1, acc[0][1], 0, 0, 0);
            acc[1][0] = MFMA(wa1, ta0, acc[1][0], 0, 0, 0);
            acc[1][1] = MFMA(wa1, ta1, acc[1][1], 0, 0, 0);
        }
    }

    __syncthreads();   // Ts/Ws dead; overlay epilogue staging
    if (!PROJ && which < 2) {
        ushort_t (*Ot)[72] = (ushort_t(*)[72])Ts;
        float bv[2] = { bias[o0 + qo + lr], bias[o0 + qo + 16 + lr] };
#pragma unroll
        for (int i = 0; i < 2; ++i)
#pragma unroll
            for (int j = 0; j < 2; ++j)
#pragma unroll
                for (int r = 0; r < 4; ++r)
                    Ot[qn + i * 16 + lg * 4 + r][qo + j * 16 + lr] = f2bf(acc[i][j][r] + bv[j]);
        __syncthreads();
        ushort_t* out = (which == 0) ? qnd : knd;
        for (int idx = tid; idx < 512; idx += 256) {
            int r = idx >> 3, sg = idx & 7;
            *(uint4*)&out[(((size_t)b * HEADS + ot) * NN + n0 + r) * HD + sg * 8] =
                *(const uint4*)&Ot[r][sg * 8];
        }
    } else if (!PROJ) {
        ushort_t (*Ot)[72] = (ushort_t(*)[72])Ts;
#pragma unroll
        for (int i = 0; i < 2; ++i)
#pragma unroll
            for (int r = 0; r < 4; ++r) {
                float bv = bias[o0 + qo + i * 16 + lg * 4 + r];
#pragma unroll
                for (int j = 0; j < 2; ++j)
                    Ot[qo + i * 16 + lg * 4 + r][qn + j * 16 + lr] = f2bf(acc[i][j][r] + bv);
            }
        __syncthreads();
        for (int idx = tid; idx < 512; idx += 256) {
            int r = idx >> 3, sg = idx & 7;
            *(uint4*)&vcn[((size_t)b * CCH + o0 + r) * NN + n0 + sg * 8] =
                *(const uint4*)&Ot[r][sg * 8];
        }
    } else {
        float (*Of)[68] = (float(*)[68])Ts;
#pragma unroll
        for (int i = 0; i < 2; ++i)
#pragma unroll
            for (int r = 0; r < 4; ++r) {
                float bv = bias[o0 + qo + i * 16 + lg * 4 + r];
#pragma unroll
                for (int j = 0; j < 2; ++j)
                    Of[qo + i * 16 + lg * 4 + r][qn + j * 16 + lr] = acc[i][j][r] + bv;
            }
        __syncthreads();
        for (int idx = tid; idx < 1024; idx += 256) {
            int r = idx >> 4, c4 = idx & 15;
            *(float4*)&outf[((size_t)b * CCH + o0 + r) * NN + n0 + c4 * 4] =
                *(const float4*)&Of[r][c4 * 4];
        }
    }
}

// ---------------------------------------------------------------------------
// MFMA flash attention, 32x32x16 shape: 4 waves x 32 q, Bc=64, kv-split x4.
// Raw exp2 (hardware v_exp_f32; shift cancels algebraically, domain safe).
// P in registers via cvt_pk + v_permlane32_swap. LDS 32KB = K dbuf + V dbuf.
// Counted-vmcnt 2-barrier pipeline.
// ---------------------------------------------------------------------------
__global__ __launch_bounds__(256, 4)
void attn_kernel(const ushort_t* __restrict__ Qnd,   // bf16 [b][h][n][d]
                 const ushort_t* __restrict__ Knd,   // bf16 [b][h][n][d] *KSCL
                 const ushort_t* __restrict__ Vcn,   // bf16 [b][c][n]
                 ushort_t* __restrict__ Op,          // bf16 [4][b][n][c]
                 float* __restrict__ Larr)           // fp32 [4][16][NN]
{
    __shared__ __align__(16) char smem[32768];

    const int tid = threadIdx.x;
    const int lin0 = blockIdx.x + 18 * blockIdx.y + 288 * blockIdx.z;
    const int w    = (lin0 & 7) * 144 + (lin0 >> 3);   // XCD-chunked remap (1152=8*144)
    const int qt = w % 18;
    const int bh = (w / 18) & 15;
    const int sp = w / 288;
    const int b = bh >> 2, h = bh & 3;
    const int lane = tid & 63, wv = tid >> 6;
    const int l31 = lane & 31, hi = lane >> 5, l7 = lane & 7;
    const int lrow = lane >> 3, lslot = (lane & 7) ^ lrow;
    const int n0 = qt * 128;
    const size_t ndb = (size_t)(b * HEADS + h) * NN * HD;
    const size_t cnb = ((size_t)b * CCH + h * HD) * NN;

    const char* kgp = (const char*)(Knd + ndb) + (size_t)(sp * 576 + wv * 16 + lrow) * 128 + lslot * 16;
    const char* vgp = (const char*)(Vcn + cnb + sp * 576) + (size_t)(wv * 16 + lrow) * (NN * 2) + lslot * 16;
    char* kls = smem + wv * 2048;
    char* vls = smem + 16384 + wv * 2048;

#define STAGE(buf, t) do { \
    const char* kp_ = kgp + (size_t)(t) * 8192; \
    const char* vp_ = vgp + (size_t)(t) * 128; \
    char* kd_ = kls + (buf) * 8192; \
    char* vd_ = vls + (buf) * 8192; \
    gload16(kp_,              kd_); \
    gload16(kp_ + 1024,       kd_ + 1024); \
    gload16(vp_,              vd_); \
    gload16(vp_ + 8 * (NN*2), vd_ + 1024); \
} while (0)

    // Q B-fragments: 32 q/wave, q = n0 + wv*32 + l31; frag ds covers d=ds*16+hi*8..+7
    bfrag qb[4];
    {
        const ushort_t* qbase = Qnd + ndb + (size_t)(n0 + wv * 32 + l31) * HD + hi * 8;
#pragma unroll
        for (int ds = 0; ds < 4; ++ds)
            qb[ds] = *(const bfrag*)&qbase[ds * 16];
    }

    f32x16 o[2];
#pragma unroll
    for (int db = 0; db < 2; ++db)
#pragma unroll
        for (int j = 0; j < 16; ++j) o[db][j] = 0.f;
    float lacc0 = 0.f, lacc1 = 0.f;

    STAGE(0, 0);

    for (int t = 0; t < 9; ++t) {
        const int cur = t & 1;
        if (t < 8) {
            STAGE(cur ^ 1, t + 1);                            // prefetch t+1
            asm volatile("s_waitcnt vmcnt(4)" ::: "memory");  // t done, t+1 flying
        } else {
            asm volatile("s_waitcnt vmcnt(0)" ::: "memory");
        }
        __builtin_amdgcn_s_barrier();
        const char* Kb = smem + cur * 8192;
        const char* Vb = smem + 16384 + cur * 8192;

        // QK + raw v_exp + in-register P fragments
        bfrag pf[4];
#pragma unroll
        for (int kb = 0; kb < 2; ++kb) {
            f32x16 s;
#pragma unroll
            for (int j = 0; j < 16; ++j) s[j] = 0.f;
            __builtin_amdgcn_s_setprio(1);
#pragma unroll
            for (int ds = 0; ds < 4; ++ds) {
                const char* ka_p = Kb + (kb * 32 + l31) * 128 + (((2 * ds + hi) ^ l7) << 4);
                bfrag ka = *(const bfrag*)ka_p;
                s = MFMA32(ka, qb[ds], s, 0, 0, 0);
            }
            __builtin_amdgcn_s_setprio(0);
            float e[16];
#pragma unroll
            for (int j = 0; j < 16; ++j) e[j] = fexp2(s[j]);
#pragma unroll
            for (int j = 0; j < 8; ++j) { lacc0 += e[2 * j]; lacc1 += e[2 * j + 1]; }
            unsigned u[4][2];
#pragma unroll
            for (int g = 0; g < 4; ++g) {
                u[g][0] = cvtpk(e[4 * g + 0], e[4 * g + 1]);
                u[g][1] = cvtpk(e[4 * g + 2], e[4 * g + 3]);
            }
#pragma unroll
            for (int ks = 0; ks < 2; ++ks) {
                asm("v_permlane32_swap_b32 %0, %1" : "+v"(u[2*ks][0]), "+v"(u[2*ks+1][0]));
                asm("v_permlane32_swap_b32 %0, %1" : "+v"(u[2*ks][1]), "+v"(u[2*ks+1][1]));
                uint4 fw = { u[2*ks][0], u[2*ks][1], u[2*ks+1][0], u[2*ks+1][1] };
                pf[kb * 2 + ks] = *(const bfrag*)&fw;
            }
        }

        // PV: O^T[64 d][32 q] += V^T * P^T
        __builtin_amdgcn_s_setprio(1);
#pragma unroll
        for (int db = 0; db < 2; ++db)
#pragma unroll
            for (int ks = 0; ks < 4; ++ks) {
                const char* va_p = Vb + (db * 32 + l31) * 128 + (((2 * ks + hi) ^ l7) << 4);
                bfrag va = *(const bfrag*)va_p;
                o[db] = MFMA32(va, pf[ks], o[db], 0, 0, 0);
            }
        __builtin_amdgcn_s_setprio(0);

        __builtin_amdgcn_s_barrier();
    }
#undef STAGE

    // l: in-lane partial + cross-half combine (both halves share q = l31)
    float lacc = lacc0 + lacc1;
    lacc += __shfl_xor(lacc, 32);
    if (hi == 0)
        Larr[(size_t)(sp * 16 + bh) * NN + n0 + wv * 32 + l31] = lacc;

    // epilogue: pack O' bf16, transpose via LDS, coalesced uint4 stores
    unsigned (*Osb)[36] = (unsigned(*)[36])smem;   // [128][36] u32
    {
        int row = wv * 32 + l31;
#pragma unroll
        for (int db = 0; db < 2; ++db)
#pragma unroll
            for (int g = 0; g < 4; ++g) {
                uint2 pk;
                pk.x = cvtpk(o[db][4 * g + 0], o[db][4 * g + 1]);
                pk.y = cvtpk(o[db][4 * g + 2], o[db][4 * g + 3]);
                *(uint2*)&Osb[row][16 * db + 4 * g + 2 * hi] = pk;
            }
    }
    __syncthreads();
    ushort_t* opb = Op + (size_t)sp * BCN + ((size_t)b * NN + n0) * CCH + h * HD;
    for (int idx = tid; idx < 1024; idx += 256) {
        int n = idx >> 3, s4 = idx & 7;
        *(uint4*)&opb[(size_t)n * CCH + s4 * 8] = *(const uint4*)&Osb[n][s4 * 4];
    }
}

// ---------------------------------------------------------------------------
// fuse: sum kv-splits (bf16 O') + depthwise 3x3 BN -> bf16 [b][n][c]
// ---------------------------------------------------------------------------
__global__ __launch_bounds__(256)
void fuse_kernel(const ushort_t* __restrict__ Op, const float* __restrict__ Larr,
                 const ushort_t* __restrict__ Qnd,
                 const ushort_t* __restrict__ pw2, const float* __restrict__ pbias,
                 ushort_t* __restrict__ yt)
{
    const int tid = threadIdx.x;
    const int b  = blockIdx.x / 288;
    const int n0 = (blockIdx.x % 288) * 8;
    const int c8 = tid & 31, ns = tid >> 5;
    const int n  = n0 + ns;
    const int h  = c8 >> 3, c0 = c8 * 8;

    const ushort_t* o0p = Op + ((size_t)b * NN + n) * CCH + c0;
    float acc[8] = {0.f, 0.f, 0.f, 0.f, 0.f, 0.f, 0.f, 0.f};
#pragma unroll
    for (int s = 0; s < NSP; ++s) {
        uint4 u = *(const uint4*)&o0p[(size_t)s * BCN];
        acc[0] += bflo(u.x); acc[1] += bfhi(u.x);
        acc[2] += bflo(u.y); acc[3] += bfhi(u.y);
        acc[4] += bflo(u.z); acc[5] += bfhi(u.z);
        acc[6] += bflo(u.w); acc[7] += bfhi(u.w);
    }
    int mi = (b * HEADS + h) * NN + n;
    float ls = 0.f;
#pragma unroll
    for (int s = 0; s < NSP; ++s) ls += Larr[(size_t)s * 16 * NN + mi];
    float rinv = 1.0f / ls;
#pragma unroll
    for (int j = 0; j < 8; ++j) acc[j] *= rinv;

    const int x = n % WW, y = n / WW;
    const ushort_t* qb = Qnd + (size_t)(b * HEADS + h) * NN * HD + (c8 & 7) * 8;
#pragma unroll
    for (int ky = 0; ky < 3; ++ky) {
        int yy = y + ky - 1;
        if (yy < 0 || yy >= HH) continue;
#pragma unroll
        for (int kx = 0; kx < 3; ++kx) {
            int xx = x + kx - 1;
            if (xx < 0 || xx >= WW) continue;
            int np = yy * WW + xx;
            uint4 qv = *(const uint4*)&qb[(size_t)np * HD];
            uint4 w4 = *(const uint4*)&pw2[(ky * 3 + kx) * CCH + c0];
            acc[0] += bflo(qv.x) * bflo(w4.x); acc[1] += bfhi(qv.x) * bfhi(w4.x);
            acc[2] += bflo(qv.y) * bflo(w4.y); acc[3] += bfhi(qv.y) * bfhi(w4.y);
            acc[4] += bflo(qv.z) * bflo(w4.z); acc[5] += bfhi(qv.z) * bfhi(w4.z);
            acc[6] += bflo(qv.w) * bflo(w4.w); acc[7] += bfhi(qv.w) * bfhi(w4.w);
        }
    }
    float4 p0 = *(const float4*)&pbias[c0];
    float4 p1 = *(const float4*)&pbias[c0 + 4];
    acc[0] += p0.x; acc[1] += p0.y; acc[2] += p0.z; acc[3] += p0.w;
    acc[4] += p1.x; acc[5] += p1.y; acc[6] += p1.z; acc[7] += p1.w;
    uint4 u;
    u.x = cvtpk(acc[0], acc[1]); u.y = cvtpk(acc[2], acc[3]);
    u.z = cvtpk(acc[4], acc[5]); u.w = cvtpk(acc[6], acc[7]);
    *(uint4*)&yt[((size_t)b * NN + n) * CCH + c0] = u;
}

// ---------------------------------------------------------------------------
extern "C" void kernel_launch(void* const* d_in, const int* in_sizes, int n_in,
                              void* d_out, int out_size, void* d_ws, size_t ws_size,
                              hipStream_t stream) {
    const float* q = (const float*)d_in[0];
    const float* k = (const float*)d_in[1];
    const float* v = (const float*)d_in[2];

    char* ws = (char*)d_ws;
    ushort_t* qnd  = (ushort_t*)(ws + 0);
    ushort_t* knd  = (ushort_t*)(ws + 4718592);
    ushort_t* vcn  = (ushort_t*)(ws + 9437184);
    ushort_t* Op   = (ushort_t*)(ws + 14155776);   // bf16 [4][BCN]
    ushort_t* yt   = (ushort_t*)(ws + 4718592);    // overlays knd after attn
    float*    Larr = (float*)   (ws + 33030144);   // [4][16][NN] fp32
    ushort_t* W4   = (ushort_t*)(ws + 33619968);
    float*    bias4= (float*)   (ws + 34144256);
    ushort_t* pw2  = (ushort_t*)(ws + 34148352);
    float*    pbias= (float*)   (ws + 34152960);

    PrepWP P;
    P.W[0] = (const float*)d_in[3]; P.W[1] = (const float*)d_in[4];
    P.W[2] = (const float*)d_in[5]; P.W[3] = (const float*)d_in[6];
    P.G[0]  = (const float*)d_in[8];  P.Bb[0] = (const float*)d_in[9];
    P.Mm[0] = (const float*)d_in[10]; P.Vv[0] = (const float*)d_in[11];
    P.G[1]  = (const float*)d_in[12]; P.Bb[1] = (const float*)d_in[13];
    P.Mm[1] = (const float*)d_in[14]; P.Vv[1] = (const float*)d_in[15];
    P.G[2]  = (const float*)d_in[16]; P.Bb[2] = (const float*)d_in[17];
    P.Mm[2] = (const float*)d_in[18]; P.Vv[2] = (const float*)d_in[19];
    P.G[3]  = (const float*)d_in[24]; P.Bb[3] = (const float*)d_in[25];
    P.Mm[3] = (const float*)d_in[26]; P.Vv[3] = (const float*)d_in[27];
    P.pew = (const float*)d_in[7];
    P.peg = (const float*)d_in[20]; P.peb = (const float*)d_in[21];
    P.pem = (const float*)d_in[22]; P.pev = (const float*)d_in[23];
    P.W4 = W4; P.bias4 = bias4; P.pw2 = pw2; P.pbias = pbias;

    prep_w<<<129, 256, 0, stream>>>(P);

    conv_gemm<0><<<dim3(36, 4, 12), 256, 0, stream>>>(q, k, v, nullptr, W4, bias4,
                                                      qnd, knd, vcn, nullptr);

    attn_kernel<<<dim3(18, 16, NSP), 256, 0, stream>>>(qnd, knd, vcn, Op, Larr);

    fuse_kernel<<<1152, 256, 0, stream>>>(Op, Larr, qnd, pw2, pbias, yt);

    conv_gemm<1><<<dim3(36, 4, 4), 256, 0, stream>>>(nullptr, nullptr, nullptr, yt, W4, bias4,
                                                     nullptr, nullptr, nullptr, (float*)d_out);
}

// Round 16
// 75.098 us; speedup vs baseline: 1.3796x; 1.0135x over previous
//
#include <hip/hip_runtime.h>
#include <math.h>

#define HEADS 4
#define HD    64
#define CCH   256
#define NB    4
#define HH    48
#define WW    48
#define NN    (HH*WW)            // 2304
#define EPSBN 1e-5f
#define KSCL  0.18033688f        // 0.125 * log2(e)  (folded into K weights/bias)
#define BCN   (NB*CCH*NN)        // 2,359,296 elements
#define NSP   4                  // kv splits

typedef unsigned short ushort_t;
typedef __attribute__((ext_vector_type(8))) short bfrag;    // 8 bf16 = 4 VGPR
typedef __attribute__((ext_vector_type(4))) float f32x4;    // 16x16 C/D
typedef __attribute__((ext_vector_type(16))) float f32x16;  // 32x32 C/D

#define MFMA   __builtin_amdgcn_mfma_f32_16x16x32_bf16
#define MFMA32 __builtin_amdgcn_mfma_f32_32x32x16_bf16

static __device__ __forceinline__ ushort_t f2bf(float x) {
    unsigned int u = __float_as_uint(x);
    unsigned int r = (u + 0x7fffu + ((u >> 16) & 1u)) >> 16;   // RNE
    return (ushort_t)r;
}
static __device__ __forceinline__ unsigned cvtpk(float lo, float hi) {
    unsigned r;
    asm("v_cvt_pk_bf16_f32 %0, %1, %2" : "=v"(r) : "v"(lo), "v"(hi));
    return r;
}
static __device__ __forceinline__ float fexp2(float x) {
    // raw v_exp_f32: safe here (|s| <= ~46 << 126; denormal flush harmless)
    float r;
    asm("v_exp_f32 %0, %1" : "=v"(r) : "v"(x));
    return r;
}
static __device__ __forceinline__ float bflo(unsigned u) { return __uint_as_float(u << 16); }
static __device__ __forceinline__ float bfhi(unsigned u) { return __uint_as_float(u & 0xffff0000u); }

static __device__ __forceinline__ void gload16(const void* g, void* l) {
    __builtin_amdgcn_global_load_lds(
        (const __attribute__((address_space(1))) void*)g,
        (__attribute__((address_space(3))) void*)l, 16, 0, 0);
}

// ---------------------------------------------------------------------------
// prep: fold BN into weights -> bf16 W'[4][256][256], bias'[4][256];
// pe weights tap-major bf16.
// ---------------------------------------------------------------------------
struct PrepWP {
    const float* W[4];
    const float* G[4]; const float* Bb[4]; const float* Mm[4]; const float* Vv[4];
    const float* pew; const float* peg; const float* peb; const float* pem; const float* pev;
    ushort_t* W4; float* bias4; ushort_t* pw2; float* pbias;
};
__global__ __launch_bounds__(256)
void prep_w(PrepWP P)
{
    const int blk = blockIdx.x, tid = threadIdx.x;
    if (blk == 128) {
        int c = tid;
        float s = P.peg[c] * rsqrtf(P.pev[c] + EPSBN);
        for (int tap = 0; tap < 9; ++tap)
            P.pw2[tap * CCH + c] = f2bf(P.pew[c * 9 + tap] * s);
        P.pbias[c] = P.peb[c] - P.pem[c] * s;
        return;
    }
    int g  = blk * 256 + tid;
    int cv = g >> 13;
    int o  = (g >> 5) & 255;
    int c8 = g & 31;
    float s  = P.G[cv][o] * rsqrtf(P.Vv[cv][o] + EPSBN);
    float s2 = (cv == 1) ? s * KSCL : s;
    const float* w = P.W[cv] + (size_t)o * CCH + c8 * 8;
    uint4 u;
    u.x = cvtpk(w[0]*s2, w[1]*s2); u.y = cvtpk(w[2]*s2, w[3]*s2);
    u.z = cvtpk(w[4]*s2, w[5]*s2); u.w = cvtpk(w[6]*s2, w[7]*s2);
    *(uint4*)&P.W4[((size_t)cv * CCH + o) * CCH + c8 * 8] = u;
    if (c8 == 0) {
        float bb = (P.Bb[cv][o] - P.Mm[cv][o] * s);
        P.bias4[cv * CCH + o] = (cv == 1) ? bb * KSCL : bb;
    }
}

// ---------------------------------------------------------------------------
// bf16 MFMA 1x1-conv GEMM, 64x64 tile, full K=256, 512 threads (8 waves).
// MODE 0 (q/k/v): stages T from fp32 [b][c][n] with in-LDS transpose+convert.
//   which = z>>2: 0(q),1(k) -> bf16 [b][h][n][d]; 2(v) -> bf16 [b][c][n].
// MODE 1 (proj): T = yt bf16 [b][n][c]; fp32 [b][c][n] -> d_out.
// Wave partition: qn = (wv>>1)*16 (4 n-blocks), qo = (wv&1)*32 (2 o-blocks).
// ---------------------------------------------------------------------------
template<int PROJ>
__global__ __launch_bounds__(512)
void conv_gemm(const float* __restrict__ qf, const float* __restrict__ kf,
               const float* __restrict__ vf, const ushort_t* __restrict__ T,
               const ushort_t* __restrict__ W4, const float* __restrict__ bias4,
               ushort_t* __restrict__ qnd, ushort_t* __restrict__ knd,
               ushort_t* __restrict__ vcn, float* __restrict__ outf)
{
    __shared__ ushort_t Ts[64][264];
    __shared__ ushort_t Ws[64][264];
    const int nt = blockIdx.x, ot = blockIdx.y, z = blockIdx.z;
    const int which = PROJ ? 3 : (z >> 2);
    const int b = z & 3;
    const int tid = threadIdx.x;
    const int n0 = nt * 64, o0 = ot * 64;
    const ushort_t* Wsrc = W4 + (size_t)which * CCH * CCH + (size_t)o0 * CCH;
    const float*    bias = bias4 + which * CCH;

    if (!PROJ) {
#pragma unroll
        for (int i = 0; i < 4; ++i) {
            int idx = tid + i * 512;
            int r = idx >> 5, c16 = idx & 31;
            *(uint4*)&Ws[r][c16 * 8] = *(const uint4*)&Wsrc[(size_t)r * CCH + c16 * 8];
        }
        const float* Xf = (which == 0) ? qf : (which == 1) ? kf : vf;
        const float* Xb = Xf + (size_t)b * CCH * NN + n0;
        const int n = tid & 63;
#pragma unroll
        for (int p = 0; p < 4; ++p) {
            int c0 = (tid >> 6) * 8 + p * 64;
            const float* src = Xb + (size_t)c0 * NN + n;
            float vv[8];
#pragma unroll
            for (int j = 0; j < 8; ++j) vv[j] = src[(size_t)j * NN];
            uint4 u;
            u.x = cvtpk(vv[0], vv[1]); u.y = cvtpk(vv[2], vv[3]);
            u.z = cvtpk(vv[4], vv[5]); u.w = cvtpk(vv[6], vv[7]);
            *(uint4*)&Ts[n][c0] = u;
        }
    } else {
        const ushort_t* Tsrc = T + ((size_t)b * NN + n0) * CCH;
#pragma unroll
        for (int i = 0; i < 4; ++i) {
            int idx = tid + i * 512;
            int r = idx >> 5, c16 = idx & 31;
            *(uint4*)&Ts[r][c16 * 8] = *(const uint4*)&Tsrc[(size_t)r * CCH + c16 * 8];
            *(uint4*)&Ws[r][c16 * 8] = *(const uint4*)&Wsrc[(size_t)r * CCH + c16 * 8];
        }
    }
    __syncthreads();
    const int wv = tid >> 6, lane = tid & 63, lr = lane & 15, lg = lane >> 4;
    const int qn = (wv >> 1) * 16, qo = (wv & 1) * 32;
    f32x4 acc[2];
    acc[0] = (f32x4){0.f, 0.f, 0.f, 0.f};
    acc[1] = (f32x4){0.f, 0.f, 0.f, 0.f};

    if (!PROJ && (z >> 2) < 2) {
#pragma unroll
        for (int k8 = 0; k8 < 8; ++k8) {
            const int kc = k8 * 32 + lg * 8;
            bfrag ta  = *(const bfrag*)&Ts[qn + lr][kc];
            bfrag wa0 = *(const bfrag*)&Ws[qo + lr][kc];
            bfrag wa1 = *(const bfrag*)&Ws[qo + 16 + lr][kc];
            acc[0] = MFMA(ta, wa0, acc[0], 0, 0, 0);
            acc[1] = MFMA(ta, wa1, acc[1], 0, 0, 0);
        }
    } else {
#pragma unroll
        for (int k8 = 0; k8 < 8; ++k8) {
            const int kc = k8 * 32 + lg * 8;
            bfrag ta  = *(const bfrag*)&Ts[qn + lr][kc];
            bfrag wa0 = *(const bfrag*)&Ws[qo + lr][kc];
            bfrag wa1 = *(const bfrag*)&Ws[qo + 16 + lr][kc];
            acc[0] = MFMA(wa0, ta, acc[0], 0, 0, 0);
            acc[1] = MFMA(wa1, ta, acc[1], 0, 0, 0);
        }
    }

    __syncthreads();   // Ts/Ws dead; overlay epilogue staging
    if (!PROJ && which < 2) {
        ushort_t (*Ot)[72] = (ushort_t(*)[72])Ts;
        float bv[2] = { bias[o0 + qo + lr], bias[o0 + qo + 16 + lr] };
#pragma unroll
        for (int j = 0; j < 2; ++j)
#pragma unroll
            for (int r = 0; r < 4; ++r)
                Ot[qn + lg * 4 + r][qo + j * 16 + lr] = f2bf(acc[j][r] + bv[j]);
        __syncthreads();
        ushort_t* out = (which == 0) ? qnd : knd;
        {
            int r = tid >> 3, sg = tid & 7;
            *(uint4*)&out[(((size_t)b * HEADS + ot) * NN + n0 + r) * HD + sg * 8] =
                *(const uint4*)&Ot[r][sg * 8];
        }
    } else if (!PROJ) {
        ushort_t (*Ot)[72] = (ushort_t(*)[72])Ts;
#pragma unroll
        for (int j = 0; j < 2; ++j)
#pragma unroll
            for (int r = 0; r < 4; ++r) {
                float bv = bias[o0 + qo + j * 16 + lg * 4 + r];
                Ot[qo + j * 16 + lg * 4 + r][qn + lr] = f2bf(acc[j][r] + bv);
            }
        __syncthreads();
        {
            int r = tid >> 3, sg = tid & 7;
            *(uint4*)&vcn[((size_t)b * CCH + o0 + r) * NN + n0 + sg * 8] =
                *(const uint4*)&Ot[r][sg * 8];
        }
    } else {
        float (*Of)[68] = (float(*)[68])Ts;
#pragma unroll
        for (int j = 0; j < 2; ++j)
#pragma unroll
            for (int r = 0; r < 4; ++r) {
                float bv = bias[o0 + qo + j * 16 + lg * 4 + r];
                Of[qo + j * 16 + lg * 4 + r][qn + lr] = acc[j][r] + bv;
            }
        __syncthreads();
#pragma unroll
        for (int i = 0; i < 2; ++i) {
            int idx = tid + i * 512;
            int r = idx >> 4, c4 = idx & 15;
            *(float4*)&outf[((size_t)b * CCH + o0 + r) * NN + n0 + c4 * 4] =
                *(const float4*)&Of[r][c4 * 4];
        }
    }
}

// ---------------------------------------------------------------------------
// MFMA flash attention, 32x32x16 shape: 4 waves x 32 q, Bc=64, kv-split x4.
// SINGLE barrier per tile: vmcnt(0) (own tile-t loads) -> barrier (tile-t
// staged everywhere AND buf[cur^1] reads finished) -> STAGE(t+1) -> compute.
// Raw v_exp_f32; P in registers via cvt_pk + v_permlane32_swap. LDS 32KB.
// ---------------------------------------------------------------------------
__global__ __launch_bounds__(256, 4)
void attn_kernel(const ushort_t* __restrict__ Qnd,   // bf16 [b][h][n][d]
                 const ushort_t* __restrict__ Knd,   // bf16 [b][h][n][d] *KSCL
                 const ushort_t* __restrict__ Vcn,   // bf16 [b][c][n]
                 ushort_t* __restrict__ Op,          // bf16 [4][b][n][c]
                 float* __restrict__ Larr)           // fp32 [4][16][NN]
{
    __shared__ __align__(16) char smem[32768];

    const int tid = threadIdx.x;
    const int lin0 = blockIdx.x + 18 * blockIdx.y + 288 * blockIdx.z;
    const int w    = (lin0 & 7) * 144 + (lin0 >> 3);   // XCD-chunked remap (1152=8*144)
    const int qt = w % 18;
    const int bh = (w / 18) & 15;
    const int sp = w / 288;
    const int b = bh >> 2, h = bh & 3;
    const int lane = tid & 63, wv = tid >> 6;
    const int l31 = lane & 31, hi = lane >> 5, l7 = lane & 7;
    const int lrow = lane >> 3, lslot = (lane & 7) ^ lrow;
    const int n0 = qt * 128;
    const size_t ndb = (size_t)(b * HEADS + h) * NN * HD;
    const size_t cnb = ((size_t)b * CCH + h * HD) * NN;

    const char* kgp = (const char*)(Knd + ndb) + (size_t)(sp * 576 + wv * 16 + lrow) * 128 + lslot * 16;
    const char* vgp = (const char*)(Vcn + cnb + sp * 576) + (size_t)(wv * 16 + lrow) * (NN * 2) + lslot * 16;
    char* kls = smem + wv * 2048;
    char* vls = smem + 16384 + wv * 2048;

#define STAGE(buf, t) do { \
    const char* kp_ = kgp + (size_t)(t) * 8192; \
    const char* vp_ = vgp + (size_t)(t) * 128; \
    char* kd_ = kls + (buf) * 8192; \
    char* vd_ = vls + (buf) * 8192; \
    gload16(kp_,              kd_); \
    gload16(kp_ + 1024,       kd_ + 1024); \
    gload16(vp_,              vd_); \
    gload16(vp_ + 8 * (NN*2), vd_ + 1024); \
} while (0)

    // Q B-fragments: 32 q/wave, q = n0 + wv*32 + l31; frag ds covers d=ds*16+hi*8..+7
    bfrag qb[4];
    {
        const ushort_t* qbase = Qnd + ndb + (size_t)(n0 + wv * 32 + l31) * HD + hi * 8;
#pragma unroll
        for (int ds = 0; ds < 4; ++ds)
            qb[ds] = *(const bfrag*)&qbase[ds * 16];
    }

    f32x16 o[2];
#pragma unroll
    for (int db = 0; db < 2; ++db)
#pragma unroll
        for (int j = 0; j < 16; ++j) o[db][j] = 0.f;
    float lacc0 = 0.f, lacc1 = 0.f;

    STAGE(0, 0);

    for (int t = 0; t < 9; ++t) {
        const int cur = t & 1;
        asm volatile("s_waitcnt vmcnt(0)" ::: "memory");   // own tile-t loads landed
        __builtin_amdgcn_s_barrier();   // tile-t staged everywhere; buf[cur^1] free
        if (t < 8) STAGE(cur ^ 1, t + 1);                  // prefetch flies over compute
        const char* Kb = smem + cur * 8192;
        const char* Vb = smem + 16384 + cur * 8192;

        // QK + raw v_exp + in-register P fragments
        bfrag pf[4];
#pragma unroll
        for (int kb = 0; kb < 2; ++kb) {
            f32x16 s;
#pragma unroll
            for (int j = 0; j < 16; ++j) s[j] = 0.f;
            __builtin_amdgcn_s_setprio(1);
#pragma unroll
            for (int ds = 0; ds < 4; ++ds) {
                const char* ka_p = Kb + (kb * 32 + l31) * 128 + (((2 * ds + hi) ^ l7) << 4);
                bfrag ka = *(const bfrag*)ka_p;
                s = MFMA32(ka, qb[ds], s, 0, 0, 0);
            }
            __builtin_amdgcn_s_setprio(0);
            float e[16];
#pragma unroll
            for (int j = 0; j < 16; ++j) e[j] = fexp2(s[j]);
#pragma unroll
            for (int j = 0; j < 8; ++j) { lacc0 += e[2 * j]; lacc1 += e[2 * j + 1]; }
            unsigned u[4][2];
#pragma unroll
            for (int g = 0; g < 4; ++g) {
                u[g][0] = cvtpk(e[4 * g + 0], e[4 * g + 1]);
                u[g][1] = cvtpk(e[4 * g + 2], e[4 * g + 3]);
            }
#pragma unroll
            for (int ks = 0; ks < 2; ++ks) {
                asm("v_permlane32_swap_b32 %0, %1" : "+v"(u[2*ks][0]), "+v"(u[2*ks+1][0]));
                asm("v_permlane32_swap_b32 %0, %1" : "+v"(u[2*ks][1]), "+v"(u[2*ks+1][1]));
                uint4 fw = { u[2*ks][0], u[2*ks][1], u[2*ks+1][0], u[2*ks+1][1] };
                pf[kb * 2 + ks] = *(const bfrag*)&fw;
            }
        }

        // PV: O^T[64 d][32 q] += V^T * P^T
        __builtin_amdgcn_s_setprio(1);
#pragma unroll
        for (int db = 0; db < 2; ++db)
#pragma unroll
            for (int ks = 0; ks < 4; ++ks) {
                const char* va_p = Vb + (db * 32 + l31) * 128 + (((2 * ks + hi) ^ l7) << 4);
                bfrag va = *(const bfrag*)va_p;
                o[db] = MFMA32(va, pf[ks], o[db], 0, 0, 0);
            }
        __builtin_amdgcn_s_setprio(0);
    }
#undef STAGE
    __builtin_amdgcn_s_barrier();   // all compute done before smem overlay

    // l: in-lane partial + cross-half combine (both halves share q = l31)
    float lacc = lacc0 + lacc1;
    lacc += __shfl_xor(lacc, 32);
    if (hi == 0)
        Larr[(size_t)(sp * 16 + bh) * NN + n0 + wv * 32 + l31] = lacc;

    // epilogue: pack O' bf16, transpose via LDS, coalesced uint4 stores
    unsigned (*Osb)[36] = (unsigned(*)[36])smem;   // [128][36] u32
    {
        int row = wv * 32 + l31;
#pragma unroll
        for (int db = 0; db < 2; ++db)
#pragma unroll
            for (int g = 0; g < 4; ++g) {
                uint2 pk;
                pk.x = cvtpk(o[db][4 * g + 0], o[db][4 * g + 1]);
                pk.y = cvtpk(o[db][4 * g + 2], o[db][4 * g + 3]);
                *(uint2*)&Osb[row][16 * db + 4 * g + 2 * hi] = pk;
            }
    }
    __syncthreads();
    ushort_t* opb = Op + (size_t)sp * BCN + ((size_t)b * NN + n0) * CCH + h * HD;
    for (int idx = tid; idx < 1024; idx += 256) {
        int n = idx >> 3, s4 = idx & 7;
        *(uint4*)&opb[(size_t)n * CCH + s4 * 8] = *(const uint4*)&Osb[n][s4 * 4];
    }
}

// ---------------------------------------------------------------------------
// fuse: sum kv-splits (bf16 O') + depthwise 3x3 BN -> bf16 [b][n][c]
// ---------------------------------------------------------------------------
__global__ __launch_bounds__(256)
void fuse_kernel(const ushort_t* __restrict__ Op, const float* __restrict__ Larr,
                 const ushort_t* __restrict__ Qnd,
                 const ushort_t* __restrict__ pw2, const float* __restrict__ pbias,
                 ushort_t* __restrict__ yt)
{
    const int tid = threadIdx.x;
    const int b  = blockIdx.x / 288;
    const int n0 = (blockIdx.x % 288) * 8;
    const int c8 = tid & 31, ns = tid >> 5;
    const int n  = n0 + ns;
    const int h  = c8 >> 3, c0 = c8 * 8;

    const ushort_t* o0p = Op + ((size_t)b * NN + n) * CCH + c0;
    float acc[8] = {0.f, 0.f, 0.f, 0.f, 0.f, 0.f, 0.f, 0.f};
#pragma unroll
    for (int s = 0; s < NSP; ++s) {
        uint4 u = *(const uint4*)&o0p[(size_t)s * BCN];
        acc[0] += bflo(u.x); acc[1] += bfhi(u.x);
        acc[2] += bflo(u.y); acc[3] += bfhi(u.y);
        acc[4] += bflo(u.z); acc[5] += bfhi(u.z);
        acc[6] += bflo(u.w); acc[7] += bfhi(u.w);
    }
    int mi = (b * HEADS + h) * NN + n;
    float ls = 0.f;
#pragma unroll
    for (int s = 0; s < NSP; ++s) ls += Larr[(size_t)s * 16 * NN + mi];
    float rinv = 1.0f / ls;
#pragma unroll
    for (int j = 0; j < 8; ++j) acc[j] *= rinv;

    const int x = n % WW, y = n / WW;
    const ushort_t* qb = Qnd + (size_t)(b * HEADS + h) * NN * HD + (c8 & 7) * 8;
#pragma unroll
    for (int ky = 0; ky < 3; ++ky) {
        int yy = y + ky - 1;
        if (yy < 0 || yy >= HH) continue;
#pragma unroll
        for (int kx = 0; kx < 3; ++kx) {
            int xx = x + kx - 1;
            if (xx < 0 || xx >= WW) continue;
            int np = yy * WW + xx;
            uint4 qv = *(const uint4*)&qb[(size_t)np * HD];
            uint4 w4 = *(const uint4*)&pw2[(ky * 3 + kx) * CCH + c0];
            acc[0] += bflo(qv.x) * bflo(w4.x); acc[1] += bfhi(qv.x) * bfhi(w4.x);
            acc[2] += bflo(qv.y) * bflo(w4.y); acc[3] += bfhi(qv.y) * bfhi(w4.y);
            acc[4] += bflo(qv.z) * bflo(w4.z); acc[5] += bfhi(qv.z) * bfhi(w4.z);
            acc[6] += bflo(qv.w) * bflo(w4.w); acc[7] += bfhi(qv.w) * bfhi(w4.w);
        }
    }
    float4 p0 = *(const float4*)&pbias[c0];
    float4 p1 = *(const float4*)&pbias[c0 + 4];
    acc[0] += p0.x; acc[1] += p0.y; acc[2] += p0.z; acc[3] += p0.w;
    acc[4] += p1.x; acc[5] += p1.y; acc[6] += p1.z; acc[7] += p1.w;
    uint4 u;
    u.x = cvtpk(acc[0], acc[1]); u.y = cvtpk(acc[2], acc[3]);
    u.z = cvtpk(acc[4], acc[5]); u.w = cvtpk(acc[6], acc[7]);
    *(uint4*)&yt[((size_t)b * NN + n) * CCH + c0] = u;
}

// ---------------------------------------------------------------------------
extern "C" void kernel_launch(void* const* d_in, const int* in_sizes, int n_in,
                              void* d_out, int out_size, void* d_ws, size_t ws_size,
                              hipStream_t stream) {
    const float* q = (const float*)d_in[0];
    const float* k = (const float*)d_in[1];
    const float* v = (const float*)d_in[2];

    char* ws = (char*)d_ws;
    ushort_t* qnd  = (ushort_t*)(ws + 0);
    ushort_t* knd  = (ushort_t*)(ws + 4718592);
    ushort_t* vcn  = (ushort_t*)(ws + 9437184);
    ushort_t* Op   = (ushort_t*)(ws + 14155776);   // bf16 [4][BCN]
    ushort_t* yt   = (ushort_t*)(ws + 4718592);    // overlays knd after attn
    float*    Larr = (float*)   (ws + 33030144);   // [4][16][NN] fp32
    ushort_t* W4   = (ushort_t*)(ws + 33619968);
    float*    bias4= (float*)   (ws + 34144256);
    ushort_t* pw2  = (ushort_t*)(ws + 34148352);
    float*    pbias= (float*)   (ws + 34152960);

    PrepWP P;
    P.W[0] = (const float*)d_in[3]; P.W[1] = (const float*)d_in[4];
    P.W[2] = (const float*)d_in[5]; P.W[3] = (const float*)d_in[6];
    P.G[0]  = (const float*)d_in[8];  P.Bb[0] = (const float*)d_in[9];
    P.Mm[0] = (const float*)d_in[10]; P.Vv[0] = (const float*)d_in[11];
    P.G[1]  = (const float*)d_in[12]; P.Bb[1] = (const float*)d_in[13];
    P.Mm[1] = (const float*)d_in[14]; P.Vv[1] = (const float*)d_in[15];
    P.G[2]  = (const float*)d_in[16]; P.Bb[2] = (const float*)d_in[17];
    P.Mm[2] = (const float*)d_in[18]; P.Vv[2] = (const float*)d_in[19];
    P.G[3]  = (const float*)d_in[24]; P.Bb[3] = (const float*)d_in[25];
    P.Mm[3] = (const float*)d_in[26]; P.Vv[3] = (const float*)d_in[27];
    P.pew = (const float*)d_in[7];
    P.peg = (const float*)d_in[20]; P.peb = (const float*)d_in[21];
    P.pem = (const float*)d_in[22]; P.pev = (const float*)d_in[23];
    P.W4 = W4; P.bias4 = bias4; P.pw2 = pw2; P.pbias = pbias;

    prep_w<<<129, 256, 0, stream>>>(P);

    conv_gemm<0><<<dim3(36, 4, 12), 512, 0, stream>>>(q, k, v, nullptr, W4, bias4,
                                                      qnd, knd, vcn, nullptr);

    attn_kernel<<<dim3(18, 16, NSP), 256, 0, stream>>>(qnd, knd, vcn, Op, Larr);

    fuse_kernel<<<1152, 256, 0, stream>>>(Op, Larr, qnd, pw2, pbias, yt);

    conv_gemm<1><<<dim3(36, 4, 4), 512, 0, stream>>>(nullptr, nullptr, nullptr, yt, W4, bias4,
                                                     nullptr, nullptr, nullptr, (float*)d_out);
}